// Round 7
// baseline (1340.365 us; speedup 1.0000x reference)
//
#include <hip/hip_runtime.h>
#include <hip/hip_bf16.h>
#include <math.h>

// Sizes
#define S 12
#define C 32
#define T 7
#define GIN 12240         // S*S*(T*S+1)
#define GOUT 4608         // S*S*C
#define EPS 1e-5f

__device__ __forceinline__ float dot4(float4 a, float4 b) {
    return a.x * b.x + a.y * b.y + a.z * b.z + a.w * b.w;
}

// ---------------- prep: build gi[3][12240]; zero stage counters ----------------
__global__ __launch_bounds__(256) void k_prep(
    const float* __restrict__ it, const float* __restrict__ is_,
    const float* __restrict__ s2w, const float* __restrict__ s2b,
    float* __restrict__ gi, int* __restrict__ cnt)
{
    int idx = blockIdx.x * 256 + threadIdx.x;
    if (idx < 24 * 12) cnt[idx] = 0;
    if (idx >= 3 * GIN) return;
    int i = idx / GIN, rem = idx % GIN;
    int ab = rem / 85, e = rem % 85;
    int a = ab / S, b = ab % S;
    float val;
    if (e < 84) {
        int k = e / T, t = e % T;
        int x, y, z;
        if (i == 0)      { x = a; y = b; z = k; }
        else if (i == 1) { x = b; y = k; z = a; }
        else             { x = k; y = a; z = b; }
        val = it[((t * S + x) * S + y) * S + z];
    } else {
        float acc = s2b[i * 144 + ab];
        const float* wr = s2w + (i * 144 + ab) * 8;
        #pragma unroll
        for (int u = 0; u < 8; u++) acc += wr[u] * is_[u];
        val = acc;
    }
    gi[idx] = val;
}

// ---------------- g2g: x[i] = W[i] @ gi[i] + b[i], one wave per row ----------------
__global__ __launch_bounds__(256) void k_g2g(
    const float* __restrict__ W, const float* __restrict__ gb,
    const float* __restrict__ gi, float* __restrict__ xbuf)
{
    int wave = threadIdx.x >> 6;
    int lane = threadIdx.x & 63;
    int r = blockIdx.x * 4 + wave;          // 0..13823
    int i = r / GOUT, rr = r % GOUT;
    const float4* Wr = reinterpret_cast<const float4*>(W + (size_t)r * GIN);
    const float4* gv = reinterpret_cast<const float4*>(gi + i * GIN);
    float acc = 0.f;
    for (int k = lane; k < GIN / 4; k += 64) {
        float4 w4 = Wr[k];
        float4 g4 = gv[k];
        acc += w4.x * g4.x + w4.y * g4.y + w4.z * g4.z + w4.w * g4.w;
    }
    #pragma unroll
    for (int off = 32; off; off >>= 1) acc += __shfl_down(acc, off, 64);
    if (lane == 0) xbuf[i * (2 * GOUT) + rr] = acc + gb[r];   // parity 0
}

// ---------------- merged stage: attn (producer) + per-slice spin + FFN (consumer) ----------------
// 192 blocks x 256 threads; block=(s,h). All blocks co-resident (192 <= 256 CUs).
// Producer: attn partial -> xpart[s][h], release-fence, cnt[s]++.
// Consumer (h<12): spin until cnt[s]==16, then FFN for rows {2h, 2h+1}.
__global__ __launch_bounds__(256) void k_stage(
    const float* __restrict__ xm1, const float* __restrict__ xm2,
    const float* __restrict__ lnxg, const float* __restrict__ lnxb,
    const float* __restrict__ lnyg, const float* __restrict__ lnyb,
    const float* __restrict__ wqw, const float* __restrict__ wqb,
    const float* __restrict__ wkw, const float* __restrict__ wkb,
    const float* __restrict__ wvw, const float* __restrict__ wvb,
    const float* __restrict__ l1w, const float* __restrict__ l1b,
    const float* __restrict__ lnfg, const float* __restrict__ lnfb,
    const float* __restrict__ l2w, const float* __restrict__ l2b,
    const float* __restrict__ l3w, const float* __restrict__ l3b,
    float* __restrict__ xpart, int* __restrict__ cnt,
    float* __restrict__ out_m1, float* __restrict__ out_m2, int l)
{
    int s = blockIdx.x >> 4, h = blockIdx.x & 15;
    int tid = threadIdx.x;
    int ls = l * S + s;
    __shared__ float a[768], xn[768], yn[768], q[768], kk[768], vv[768], oo[768];
    __shared__ float sc[576];
    __shared__ float red[16];

    // ======== attention (exact round-1/6 body) ========
    for (int idx = tid; idx < 768; idx += 256) {
        int r = idx >> 5, c = idx & 31;
        a[idx] = (r < S) ? xm1[s * 384 + r * 32 + c]
                         : xm2[(r - S) * 384 + s * 32 + c];
    }
    __syncthreads();

    {
        float s1 = 0.f, s2 = 0.f;
        for (int idx = tid; idx < 768; idx += 256) { float z = a[idx]; s1 += z; s2 += z * z; }
        #pragma unroll
        for (int off = 32; off; off >>= 1) { s1 += __shfl_down(s1, off, 64); s2 += __shfl_down(s2, off, 64); }
        if ((tid & 63) == 0) { red[(tid >> 6) * 2] = s1; red[(tid >> 6) * 2 + 1] = s2; }
        __syncthreads();
        if (tid == 0) {
            float t1 = red[0] + red[2] + red[4] + red[6];
            float t2 = red[1] + red[3] + red[5] + red[7];
            float mu = t1 * (1.f / 768.f);
            float var = t2 * (1.f / 768.f) - mu * mu;
            red[8] = mu;
            red[9] = rsqrtf(var + EPS);
        }
        __syncthreads();
    }
    float mu = red[8], rs = red[9];

    const float* gx = lnxg + ls * 768; const float* bx = lnxb + ls * 768;
    const float* gy = lnyg + ls * 768; const float* by = lnyb + ls * 768;
    for (int idx = tid; idx < 768; idx += 256) {
        float zn = (a[idx] - mu) * rs;
        xn[idx] = zn * gx[idx] + bx[idx];
        yn[idx] = zn * gy[idx] + by[idx];
    }
    __syncthreads();

    const float4* wq4 = (const float4*)(wqw + (size_t)ls * 16384 + h * 1024);
    const float4* wk4 = (const float4*)(wkw + (size_t)ls * 16384 + h * 1024);
    const float4* wv4 = (const float4*)(wvw + (size_t)ls * 16384 + h * 1024);
    const float* qb = wqb + ls * 512 + h * 32;
    const float* kb = wkb + ls * 512 + h * 32;
    const float* vb = wvb + ls * 512 + h * 32;
    for (int idx = tid; idx < 768; idx += 256) {
        int r = idx >> 5, j = idx & 31;
        const float4* xr = (const float4*)(xn + r * 32);
        const float4* yr = (const float4*)(yn + r * 32);
        float aq = qb[j], ak = kb[j], av = vb[j];
        #pragma unroll
        for (int c4 = 0; c4 < 8; c4++) {
            float4 xv = xr[c4], yv = yr[c4];
            aq += dot4(xv, wq4[j * 8 + c4]);
            ak += dot4(yv, wk4[j * 8 + c4]);
            av += dot4(yv, wv4[j * 8 + c4]);
        }
        q[idx] = aq; kk[idx] = ak; vv[idx] = av;
    }
    __syncthreads();

    for (int idx = tid; idx < 576; idx += 256) {
        int r = idx / 24, j = idx - r * 24;
        const float4* qr = (const float4*)(q + r * 32);
        const float4* kr = (const float4*)(kk + j * 32);
        float acc = 0.f;
        #pragma unroll
        for (int c4 = 0; c4 < 8; c4++) acc += dot4(qr[c4], kr[c4]);
        sc[idx] = acc * 0.17677669529663687f;   // 1/sqrt(32)
    }
    __syncthreads();

    for (int idx = tid; idx < 768; idx += 256) {
        int r = idx >> 5, c = idx & 31;
        const float* sr = sc + r * 24;
        float acc = 0.f;
        #pragma unroll
        for (int j = 0; j < 24; j++) acc += sr[j] * vv[j * 32 + c];
        oo[idx] = acc;
    }
    __syncthreads();

    const float4* w14 = (const float4*)(l1w + (size_t)ls * 16384 + h * 32);
    float* xp = xpart + (s * 16 + h) * 768;
    for (int idx = tid; idx < 768; idx += 256) {
        int r = idx >> 5, j = idx & 31;
        const float4* orow = (const float4*)(oo + r * 32);
        float acc = 0.f;
        #pragma unroll
        for (int c4 = 0; c4 < 8; c4++) acc += dot4(orow[c4], w14[j * 128 + c4]);
        xp[idx] = acc;
    }

    // ======== release: xpart visible, then count ========
    __threadfence();
    __syncthreads();
    if (tid == 0)
        __hip_atomic_fetch_add(&cnt[s], 1, __ATOMIC_RELEASE, __HIP_MEMORY_SCOPE_AGENT);
    if (h >= 12) return;

    // ======== consumer: spin until all 16 heads of slice s done ========
    if (tid == 0) {
        while (__hip_atomic_load(&cnt[s], __ATOMIC_ACQUIRE, __HIP_MEMORY_SCOPE_AGENT) < 16)
            __builtin_amdgcn_s_sleep(2);
    }
    __syncthreads();
    __threadfence();   // acquire: invalidate L1 before reading other blocks' xpart

    // ======== FFN for rows {2h, 2h+1} (a[] reused from LDS) ========
    float* x   = q;            // 768, reuse
    float* hn2 = kk;           // 64
    float* g2  = kk + 64;      // 256
    int r0 = h * 2;

    for (int idx = tid; idx < 768; idx += 256) {
        int c = idx & 31;
        float acc = a[idx] + l1b[ls * 32 + c];
        const float* xpr = xpart + s * 16 * 768 + idx;
        #pragma unroll
        for (int hh = 0; hh < 16; hh++) acc += xpr[hh * 768];
        x[idx] = acc;
    }
    __syncthreads();

    {
        float s1 = 0.f, s2 = 0.f;
        for (int idx = tid; idx < 768; idx += 256) { float z = x[idx]; s1 += z; s2 += z * z; }
        #pragma unroll
        for (int off = 32; off; off >>= 1) { s1 += __shfl_down(s1, off, 64); s2 += __shfl_down(s2, off, 64); }
        if ((tid & 63) == 0) { red[(tid >> 6) * 2] = s1; red[(tid >> 6) * 2 + 1] = s2; }
        __syncthreads();
        if (tid == 0) {
            float t1 = red[0] + red[2] + red[4] + red[6];
            float t2 = red[1] + red[3] + red[5] + red[7];
            float m = t1 * (1.f / 768.f);
            float v = t2 * (1.f / 768.f) - m * m;
            red[8] = m;
            red[9] = rsqrtf(v + EPS);
        }
        __syncthreads();
    }
    float mu2 = red[8], rs2 = red[9];

    if (tid < 64) {
        int r = r0 + (tid >> 5), c = tid & 31;
        int idx = r * 32 + c;
        hn2[tid] = (x[idx] - mu2) * rs2 * lnfg[ls * 768 + idx] + lnfb[ls * 768 + idx];
    }
    __syncthreads();

    {
        int rr = tid >> 7, u = tid & 127;
        const float4* hr = (const float4*)(hn2 + rr * 32);
        const float4* w2r = (const float4*)(l2w + (size_t)ls * 4096 + u * 32);
        float acc = l2b[ls * 128 + u];
        #pragma unroll
        for (int c4 = 0; c4 < 8; c4++) acc += dot4(hr[c4], w2r[c4]);
        g2[rr * 128 + u] = acc * 0.5f * (1.f + erff(acc * 0.70710678118654752f));
    }
    __syncthreads();

    {
        int oi = tid >> 2, qq = tid & 3;     // 64 outputs x 4 lanes
        int rr = oi >> 5, j = oi & 31;
        int r = r0 + rr;
        const float4* gr  = (const float4*)(g2 + rr * 128);
        const float4* w3r = (const float4*)(l3w + (size_t)ls * 4096 + j * 128);
        float p = 0.f;
        #pragma unroll
        for (int u4 = qq * 8; u4 < qq * 8 + 8; u4++) p += dot4(gr[u4], w3r[u4]);
        p += __shfl_down(p, 2, 4);
        p += __shfl_down(p, 1, 4);
        if (qq == 0) {
            float val = x[r * 32 + j] + l3b[ls * 32 + j] + p;
            if (r < S) out_m1[s * 384 + r * 32 + j] = val;
            else       out_m2[s * 384 + (r - S) * 32 + j] = val;
        }
    }
}

// ---------------- pack: out[(a*3+i)*12+b][c] = x_i[a][b][c] ----------------
__global__ __launch_bounds__(256) void k_pack(
    const float* __restrict__ x0, const float* __restrict__ x1,
    const float* __restrict__ x2, float* __restrict__ out)
{
    int idx = blockIdx.x * 256 + threadIdx.x;
    if (idx >= 3 * 144 * 32) return;
    int c = idx & 31;
    int r = idx >> 5;
    int b = r % 12;
    int ai = r / 12;
    int i = ai % 3;
    int a = ai / 3;
    const float* xs = (i == 0) ? x0 : ((i == 1) ? x1 : x2);
    out[idx] = xs[a * 384 + b * 32 + c];
}

extern "C" void kernel_launch(void* const* d_in, const int* in_sizes, int n_in,
                              void* d_out, int out_size, void* d_ws, size_t ws_size,
                              hipStream_t stream) {
    const float* input_t = (const float*)d_in[0];
    const float* input_s = (const float*)d_in[1];
    const float* s2g_w   = (const float*)d_in[2];
    const float* s2g_b   = (const float*)d_in[3];
    const float* g2g_w   = (const float*)d_in[4];
    const float* g2g_b   = (const float*)d_in[5];
    const float* lnx_g   = (const float*)d_in[6];
    const float* lnx_b   = (const float*)d_in[7];
    const float* lny_g   = (const float*)d_in[8];
    const float* lny_b   = (const float*)d_in[9];
    const float* lnf_g   = (const float*)d_in[10];
    const float* lnf_b   = (const float*)d_in[11];
    const float* wq_w    = (const float*)d_in[12];
    const float* wq_b    = (const float*)d_in[13];
    const float* wk_w    = (const float*)d_in[14];
    const float* wk_b    = (const float*)d_in[15];
    const float* wv_w    = (const float*)d_in[16];
    const float* wv_b    = (const float*)d_in[17];
    const float* l1_w    = (const float*)d_in[18];
    const float* l1_b    = (const float*)d_in[19];
    const float* l2_w    = (const float*)d_in[20];
    const float* l2_b    = (const float*)d_in[21];
    const float* l3_w    = (const float*)d_in[22];
    const float* l3_b    = (const float*)d_in[23];

    float* ws = (float*)d_ws;
    float* gi    = ws;                       // 3*12240 = 36720
    float* xbuf  = ws + 36720;               // 3*2*4608 = 27648
    float* xpart = ws + 36720 + 27648;       // 12*16*768 = 147456
    int*   cnt   = (int*)(ws + 211824);      // 24*12 counters

    k_prep<<<144, 256, 0, stream>>>(input_t, input_s, s2g_w, s2g_b, gi, cnt);
    k_g2g<<<3456, 256, 0, stream>>>(g2g_w, g2g_b, gi, xbuf);

    int par[3] = {0, 0, 0};
    const int pairs[3][2] = {{0, 1}, {2, 0}, {1, 2}};
    for (int l = 0; l < 8; l++) {
        for (int pp = 0; pp < 3; pp++) {
            int m1 = pairs[pp][0], m2 = pairs[pp][1];
            int stage = l * 3 + pp;
            float* in1  = xbuf + m1 * 9216 + par[m1] * 4608;
            float* in2  = xbuf + m2 * 9216 + par[m2] * 4608;
            float* out1 = xbuf + m1 * 9216 + (1 - par[m1]) * 4608;
            float* out2 = xbuf + m2 * 9216 + (1 - par[m2]) * 4608;
            k_stage<<<192, 256, 0, stream>>>(in1, in2,
                lnx_g, lnx_b, lny_g, lny_b,
                wq_w, wq_b, wk_w, wk_b, wv_w, wv_b,
                l1_w, l1_b, lnf_g, lnf_b,
                l2_w, l2_b, l3_w, l3_b,
                xpart, cnt + stage * 12, out1, out2, l);
            par[m1] ^= 1; par[m2] ^= 1;
        }
    }
    k_pack<<<54, 256, 0, stream>>>(
        xbuf + 0 * 9216 + par[0] * 4608,
        xbuf + 1 * 9216 + par[1] * 4608,
        xbuf + 2 * 9216 + par[2] * 4608,
        (float*)d_out);
}

// Round 8
// 643.865 us; speedup vs baseline: 2.0818x; 2.0818x over previous
//
#include <hip/hip_runtime.h>
#include <hip/hip_bf16.h>
#include <math.h>

// Sizes
#define S 12
#define C 32
#define T 7
#define GIN 12240         // S*S*(T*S+1)
#define GOUT 4608         // S*S*C
#define EPS 1e-5f

__device__ __forceinline__ float dot4(float4 a, float4 b) {
    return a.x * b.x + a.y * b.y + a.z * b.z + a.w * b.w;
}

// ---------------- prep: build gi[3][12240] ----------------
__global__ __launch_bounds__(256) void k_prep(
    const float* __restrict__ it, const float* __restrict__ is_,
    const float* __restrict__ s2w, const float* __restrict__ s2b,
    float* __restrict__ gi)
{
    int idx = blockIdx.x * 256 + threadIdx.x;
    if (idx >= 3 * GIN) return;
    int i = idx / GIN, rem = idx % GIN;
    int ab = rem / 85, e = rem % 85;
    int a = ab / S, b = ab % S;
    float val;
    if (e < 84) {
        int k = e / T, t = e % T;
        int x, y, z;
        if (i == 0)      { x = a; y = b; z = k; }
        else if (i == 1) { x = b; y = k; z = a; }
        else             { x = k; y = a; z = b; }
        val = it[((t * S + x) * S + y) * S + z];
    } else {
        float acc = s2b[i * 144 + ab];
        const float* wr = s2w + (i * 144 + ab) * 8;
        #pragma unroll
        for (int u = 0; u < 8; u++) acc += wr[u] * is_[u];
        val = acc;
    }
    gi[idx] = val;
}

// ---------------- g2g: x[i] = W[i] @ gi[i] + b[i], one wave per row ----------------
__global__ __launch_bounds__(256) void k_g2g(
    const float* __restrict__ W, const float* __restrict__ gb,
    const float* __restrict__ gi, float* __restrict__ xbuf)
{
    int wave = threadIdx.x >> 6;
    int lane = threadIdx.x & 63;
    int r = blockIdx.x * 4 + wave;          // 0..13823
    int i = r / GOUT, rr = r % GOUT;
    const float4* Wr = reinterpret_cast<const float4*>(W + (size_t)r * GIN);
    const float4* gv = reinterpret_cast<const float4*>(gi + i * GIN);
    float acc = 0.f;
    for (int k = lane; k < GIN / 4; k += 64) {
        float4 w4 = Wr[k];
        float4 g4 = gv[k];
        acc += w4.x * g4.x + w4.y * g4.y + w4.z * g4.z + w4.w * g4.w;
    }
    #pragma unroll
    for (int off = 32; off; off >>= 1) acc += __shfl_down(acc, off, 64);
    if (lane == 0) xbuf[i * (2 * GOUT) + rr] = acc + gb[r];   // parity 0
}

// ---------------- K1: per (slice, head): LN + QKV + scores + O + W1 partial ----------------
// Round-6 body with fused LN stats (stats accumulated during load; one barrier).
__global__ __launch_bounds__(256) void k_attn(
    const float* __restrict__ xm1, const float* __restrict__ xm2,
    const float* __restrict__ lnxg, const float* __restrict__ lnxb,
    const float* __restrict__ lnyg, const float* __restrict__ lnyb,
    const float* __restrict__ wqw, const float* __restrict__ wqb,
    const float* __restrict__ wkw, const float* __restrict__ wkb,
    const float* __restrict__ wvw, const float* __restrict__ wvb,
    const float* __restrict__ l1w,
    float* __restrict__ xpart, int l)
{
    int s = blockIdx.x >> 4, h = blockIdx.x & 15;
    int tid = threadIdx.x;
    int ls = l * S + s;
    __shared__ float a[768], xn[768], yn[768], q[768], kk[768], vv[768], oo[768];
    __shared__ float sc[576];
    __shared__ float red[16];

    // ---- load a + accumulate LN partials in the same pass ----
    {
        float s1 = 0.f, s2 = 0.f;
        for (int idx = tid; idx < 768; idx += 256) {
            int r = idx >> 5, c = idx & 31;
            float v = (r < S) ? xm1[s * 384 + r * 32 + c]
                              : xm2[(r - S) * 384 + s * 32 + c];
            a[idx] = v;
            s1 += v; s2 += v * v;
        }
        #pragma unroll
        for (int off = 32; off; off >>= 1) { s1 += __shfl_down(s1, off, 64); s2 += __shfl_down(s2, off, 64); }
        if ((tid & 63) == 0) { red[(tid >> 6) * 2] = s1; red[(tid >> 6) * 2 + 1] = s2; }
    }
    __syncthreads();   // publishes a[] and red[]

    float mu, rs;
    {
        float t1 = red[0] + red[2] + red[4] + red[6];
        float t2 = red[1] + red[3] + red[5] + red[7];
        mu = t1 * (1.f / 768.f);
        float var = t2 * (1.f / 768.f) - mu * mu;
        rs = rsqrtf(var + EPS);
    }

    const float* gx = lnxg + ls * 768; const float* bx = lnxb + ls * 768;
    const float* gy = lnyg + ls * 768; const float* by = lnyb + ls * 768;
    for (int idx = tid; idx < 768; idx += 256) {
        float zn = (a[idx] - mu) * rs;
        xn[idx] = zn * gx[idx] + bx[idx];
        yn[idx] = zn * gy[idx] + by[idx];
    }
    __syncthreads();

    const float4* wq4 = (const float4*)(wqw + (size_t)ls * 16384 + h * 1024);
    const float4* wk4 = (const float4*)(wkw + (size_t)ls * 16384 + h * 1024);
    const float4* wv4 = (const float4*)(wvw + (size_t)ls * 16384 + h * 1024);
    const float* qb = wqb + ls * 512 + h * 32;
    const float* kb = wkb + ls * 512 + h * 32;
    const float* vb = wvb + ls * 512 + h * 32;
    for (int idx = tid; idx < 768; idx += 256) {
        int r = idx >> 5, j = idx & 31;
        const float4* xr = (const float4*)(xn + r * 32);
        const float4* yr = (const float4*)(yn + r * 32);
        float aq = qb[j], ak = kb[j], av = vb[j];
        #pragma unroll
        for (int c4 = 0; c4 < 8; c4++) {
            float4 xv = xr[c4], yv = yr[c4];
            aq += dot4(xv, wq4[j * 8 + c4]);
            ak += dot4(yv, wk4[j * 8 + c4]);
            av += dot4(yv, wv4[j * 8 + c4]);
        }
        q[idx] = aq; kk[idx] = ak; vv[idx] = av;
    }
    __syncthreads();

    for (int idx = tid; idx < 576; idx += 256) {
        int r = idx / 24, j = idx - r * 24;
        const float4* qr = (const float4*)(q + r * 32);
        const float4* kr = (const float4*)(kk + j * 32);
        float acc = 0.f;
        #pragma unroll
        for (int c4 = 0; c4 < 8; c4++) acc += dot4(qr[c4], kr[c4]);
        sc[idx] = acc * 0.17677669529663687f;   // 1/sqrt(32)
    }
    __syncthreads();

    for (int idx = tid; idx < 768; idx += 256) {
        int r = idx >> 5, c = idx & 31;
        const float* sr = sc + r * 24;
        float acc = 0.f;
        #pragma unroll
        for (int j = 0; j < 24; j++) acc += sr[j] * vv[j * 32 + c];
        oo[idx] = acc;
    }
    __syncthreads();

    const float4* w14 = (const float4*)(l1w + (size_t)ls * 16384 + h * 32);
    float* xp = xpart + (s * 16 + h) * 768;
    for (int idx = tid; idx < 768; idx += 256) {
        int r = idx >> 5, j = idx & 31;
        const float4* orow = (const float4*)(oo + r * 32);
        float acc = 0.f;
        #pragma unroll
        for (int c4 = 0; c4 < 8; c4++) acc += dot4(orow[c4], w14[j * 128 + c4]);
        xp[idx] = acc;
    }
}

// ---------------- K2: r-split FFN, 144 blocks x 256 threads ----------------
// Fused LN stats; optional packed d_out dual-write for final-writer stages
// (i1/i2 = matrix index in the packed output, or -1).
__global__ __launch_bounds__(256) void k_ffn(
    const float* __restrict__ xm1, const float* __restrict__ xm2,
    const float* __restrict__ xpart,
    const float* __restrict__ l1b,
    const float* __restrict__ lnfg, const float* __restrict__ lnfb,
    const float* __restrict__ l2w, const float* __restrict__ l2b,
    const float* __restrict__ l3w, const float* __restrict__ l3b,
    float* __restrict__ out_m1, float* __restrict__ out_m2,
    float* __restrict__ outp, int i1, int i2, int l)
{
    int s = blockIdx.x / 12, rg = blockIdx.x % 12;
    int r0 = rg * 2;
    int tid = threadIdx.x;
    int ls = l * S + s;
    __shared__ float x[768], hn2[64], g2[256];
    __shared__ float red[16];

    // ---- x = a + b1 + sum of 16 head partials, LN partials fused ----
    {
        float s1 = 0.f, s2 = 0.f;
        for (int idx = tid; idx < 768; idx += 256) {
            int r = idx >> 5, c = idx & 31;
            float av = (r < S) ? xm1[s * 384 + r * 32 + c]
                               : xm2[(r - S) * 384 + s * 32 + c];
            float acc = av + l1b[ls * 32 + c];
            const float* xp = xpart + s * 16 * 768 + idx;
            #pragma unroll
            for (int hh = 0; hh < 16; hh++) acc += xp[hh * 768];
            x[idx] = acc;
            s1 += acc; s2 += acc * acc;
        }
        #pragma unroll
        for (int off = 32; off; off >>= 1) { s1 += __shfl_down(s1, off, 64); s2 += __shfl_down(s2, off, 64); }
        if ((tid & 63) == 0) { red[(tid >> 6) * 2] = s1; red[(tid >> 6) * 2 + 1] = s2; }
    }
    __syncthreads();   // publishes x[] and red[]

    float mu, rs;
    {
        float t1 = red[0] + red[2] + red[4] + red[6];
        float t2 = red[1] + red[3] + red[5] + red[7];
        mu = t1 * (1.f / 768.f);
        float var = t2 * (1.f / 768.f) - mu * mu;
        rs = rsqrtf(var + EPS);
    }

    // ---- LN apply for own 2 rows only ----
    if (tid < 64) {
        int r = r0 + (tid >> 5), c = tid & 31;
        int idx = r * 32 + c;
        hn2[tid] = (x[idx] - mu) * rs * lnfg[ls * 768 + idx] + lnfb[ls * 768 + idx];
    }
    __syncthreads();

    // ---- g2 = gelu(hn2 @ W2^T + b2): 2 rows x 128 dots, 1/thread ----
    {
        int rr = tid >> 7, u = tid & 127;
        const float4* hr = (const float4*)(hn2 + rr * 32);
        const float4* w2r = (const float4*)(l2w + (size_t)ls * 4096 + u * 32);
        float acc = l2b[ls * 128 + u];
        #pragma unroll
        for (int c4 = 0; c4 < 8; c4++) acc += dot4(hr[c4], w2r[c4]);
        g2[rr * 128 + u] = acc * 0.5f * (1.f + erff(acc * 0.70710678118654752f));
    }
    __syncthreads();

    // ---- out = x + g2 @ W3^T + b3 for own 2 rows (4-way u-split per output) ----
    {
        int oi = tid >> 2, qq = tid & 3;     // 64 outputs x 4 lanes
        int rr = oi >> 5, j = oi & 31;
        int r = r0 + rr;
        const float4* gr  = (const float4*)(g2 + rr * 128);
        const float4* w3r = (const float4*)(l3w + (size_t)ls * 4096 + j * 128);
        float p = 0.f;
        #pragma unroll
        for (int u4 = qq * 8; u4 < qq * 8 + 8; u4++) p += dot4(gr[u4], w3r[u4]);
        p += __shfl_down(p, 2, 4);
        p += __shfl_down(p, 1, 4);
        if (qq == 0) {
            float val = x[r * 32 + j] + l3b[ls * 32 + j] + p;
            if (r < S) {
                out_m1[s * 384 + r * 32 + j] = val;
                if (i1 >= 0) outp[((s * 3 + i1) * 12 + r) * 32 + j] = val;
            } else {
                out_m2[s * 384 + (r - S) * 32 + j] = val;
                if (i2 >= 0) outp[((s * 3 + i2) * 12 + (r - S)) * 32 + j] = val;
            }
        }
    }
}

extern "C" void kernel_launch(void* const* d_in, const int* in_sizes, int n_in,
                              void* d_out, int out_size, void* d_ws, size_t ws_size,
                              hipStream_t stream) {
    const float* input_t = (const float*)d_in[0];
    const float* input_s = (const float*)d_in[1];
    const float* s2g_w   = (const float*)d_in[2];
    const float* s2g_b   = (const float*)d_in[3];
    const float* g2g_w   = (const float*)d_in[4];
    const float* g2g_b   = (const float*)d_in[5];
    const float* lnx_g   = (const float*)d_in[6];
    const float* lnx_b   = (const float*)d_in[7];
    const float* lny_g   = (const float*)d_in[8];
    const float* lny_b   = (const float*)d_in[9];
    const float* lnf_g   = (const float*)d_in[10];
    const float* lnf_b   = (const float*)d_in[11];
    const float* wq_w    = (const float*)d_in[12];
    const float* wq_b    = (const float*)d_in[13];
    const float* wk_w    = (const float*)d_in[14];
    const float* wk_b    = (const float*)d_in[15];
    const float* wv_w    = (const float*)d_in[16];
    const float* wv_b    = (const float*)d_in[17];
    const float* l1_w    = (const float*)d_in[18];
    const float* l1_b    = (const float*)d_in[19];
    const float* l2_w    = (const float*)d_in[20];
    const float* l2_b    = (const float*)d_in[21];
    const float* l3_w    = (const float*)d_in[22];
    const float* l3_b    = (const float*)d_in[23];

    float* ws = (float*)d_ws;
    float* gi    = ws;                       // 3*12240 = 36720
    float* xbuf  = ws + 36720;               // 3*2*4608 = 27648
    float* xpart = ws + 36720 + 27648;       // 12*16*768 = 147456
    float* outp  = (float*)d_out;

    k_prep<<<144, 256, 0, stream>>>(input_t, input_s, s2g_w, s2g_b, gi);
    k_g2g<<<3456, 256, 0, stream>>>(g2g_w, g2g_b, gi, xbuf);

    int par[3] = {0, 0, 0};
    const int pairs[3][2] = {{0, 1}, {2, 0}, {1, 2}};
    for (int l = 0; l < 8; l++) {
        for (int pp = 0; pp < 3; pp++) {
            int m1 = pairs[pp][0], m2 = pairs[pp][1];
            float* in1  = xbuf + m1 * 9216 + par[m1] * 4608;
            float* in2  = xbuf + m2 * 9216 + par[m2] * 4608;
            float* out1 = xbuf + m1 * 9216 + (1 - par[m1]) * 4608;
            float* out2 = xbuf + m2 * 9216 + (1 - par[m2]) * 4608;
            // final-writer stages dual-write packed d_out:
            //   x0 final: l=7, pp=1 (pair (2,0)) as m2 -> i2=0
            //   x1 final: l=7, pp=2 (pair (1,2)) as m1 -> i1=1
            //   x2 final: l=7, pp=2 (pair (1,2)) as m2 -> i2=2
            int i1 = -1, i2 = -1;
            if (l == 7 && pp == 1) i2 = 0;
            if (l == 7 && pp == 2) { i1 = 1; i2 = 2; }
            k_attn<<<192, 256, 0, stream>>>(in1, in2,
                lnx_g, lnx_b, lny_g, lny_b,
                wq_w, wq_b, wk_w, wk_b, wv_w, wv_b,
                l1_w, xpart, l);
            k_ffn<<<144, 256, 0, stream>>>(in1, in2, xpart, l1_b,
                lnf_g, lnf_b, l2_w, l2_b, l3_w, l3_b,
                out1, out2, outp, i1, i2, l);
            par[m1] ^= 1; par[m2] ^= 1;
        }
    }
}

// Round 9
// 547.538 us; speedup vs baseline: 2.4480x; 1.1759x over previous
//
#include <hip/hip_runtime.h>
#include <hip/hip_bf16.h>
#include <math.h>

// Sizes
#define S 12
#define C 32
#define T 7
#define GIN 12240         // S*S*(T*S+1)
#define GOUT 4608         // S*S*C
#define EPS 1e-5f

__device__ __forceinline__ float dot4(float4 a, float4 b) {
    return a.x * b.x + a.y * b.y + a.z * b.z + a.w * b.w;
}

// ---------------- prep: build gi[3][12240] ----------------
__global__ __launch_bounds__(256) void k_prep(
    const float* __restrict__ it, const float* __restrict__ is_,
    const float* __restrict__ s2w, const float* __restrict__ s2b,
    float* __restrict__ gi)
{
    int idx = blockIdx.x * 256 + threadIdx.x;
    if (idx >= 3 * GIN) return;
    int i = idx / GIN, rem = idx % GIN;
    int ab = rem / 85, e = rem % 85;
    int a = ab / S, b = ab % S;
    float val;
    if (e < 84) {
        int k = e / T, t = e % T;
        int x, y, z;
        if (i == 0)      { x = a; y = b; z = k; }
        else if (i == 1) { x = b; y = k; z = a; }
        else             { x = k; y = a; z = b; }
        val = it[((t * S + x) * S + y) * S + z];
    } else {
        float acc = s2b[i * 144 + ab];
        const float* wr = s2w + (i * 144 + ab) * 8;
        #pragma unroll
        for (int u = 0; u < 8; u++) acc += wr[u] * is_[u];
        val = acc;
    }
    gi[idx] = val;
}

// ---------------- g2g: x[i] = W[i] @ gi[i] + b[i], one wave per row ----------------
__global__ __launch_bounds__(256) void k_g2g(
    const float* __restrict__ W, const float* __restrict__ gb,
    const float* __restrict__ gi, float* __restrict__ xbuf)
{
    int wave = threadIdx.x >> 6;
    int lane = threadIdx.x & 63;
    int r = blockIdx.x * 4 + wave;          // 0..13823
    int i = r / GOUT, rr = r % GOUT;
    const float4* Wr = reinterpret_cast<const float4*>(W + (size_t)r * GIN);
    const float4* gv = reinterpret_cast<const float4*>(gi + i * GIN);
    float acc = 0.f;
    for (int k = lane; k < GIN / 4; k += 64) {
        float4 w4 = Wr[k];
        float4 g4 = gv[k];
        acc += w4.x * g4.x + w4.y * g4.y + w4.z * g4.z + w4.w * g4.w;
    }
    #pragma unroll
    for (int off = 32; off; off >>= 1) acc += __shfl_down(acc, off, 64);
    if (lane == 0) xbuf[i * (2 * GOUT) + rr] = acc + gb[r];   // parity 0
}

// ---------------- K1: per (slice, head): LN + QKV + scores + O + W1 partial ----------------
// R8 body + async prefetch: a-loads issued first, then all per-block params
// (weights -> regs -> LDS staged with padded rows; LN gains/biases -> regs).
__global__ __launch_bounds__(256) void k_attn(
    const float* __restrict__ xm1, const float* __restrict__ xm2,
    const float* __restrict__ lnxg, const float* __restrict__ lnxb,
    const float* __restrict__ lnyg, const float* __restrict__ lnyb,
    const float* __restrict__ wqw, const float* __restrict__ wqb,
    const float* __restrict__ wkw, const float* __restrict__ wkb,
    const float* __restrict__ wvw, const float* __restrict__ wvb,
    const float* __restrict__ l1w,
    float* __restrict__ xpart, int l)
{
    int s = blockIdx.x >> 4, h = blockIdx.x & 15;
    int tid = threadIdx.x;
    int ls = l * S + s;
    int jj = tid & 31;
    int rb = tid >> 5;                 // base row; owns rows rb, rb+8, rb+16
    __shared__ float xn[768], yn[768], q[768], kk[768], vv[768], oo[768];
    __shared__ float sc[576];
    __shared__ float red[16];
    __shared__ float wqs[1152], wks[1152], wvs[1152], w1s[1152];   // [32][36] padded

    // ---- a-loads issued FIRST (their wait doesn't include the prefetches) ----
    int r1 = (tid + 256) >> 5;
    float av0 = xm1[s * 384 + rb * 32 + jj];                        // rows 0..7
    float av1 = (r1 < S) ? xm1[s * 384 + r1 * 32 + jj]
                         : xm2[(r1 - S) * 384 + s * 32 + jj];       // rows 8..15
    float av2 = xm2[(((tid + 512) >> 5) - S) * 384 + s * 32 + jj];  // rows 16..23

    // ---- prefetch: LN gains/biases (12 scalars), QKV biases (3), weights (4 x float4) ----
    const float* gx = lnxg + ls * 768; const float* bx = lnxb + ls * 768;
    const float* gy = lnyg + ls * 768; const float* by = lnyb + ls * 768;
    float gx0 = gx[tid], gx1 = gx[tid + 256], gx2 = gx[tid + 512];
    float bx0 = bx[tid], bx1 = bx[tid + 256], bx2 = bx[tid + 512];
    float gy0 = gy[tid], gy1 = gy[tid + 256], gy2 = gy[tid + 512];
    float by0 = by[tid], by1 = by[tid + 256], by2 = by[tid + 512];
    float qbv = wqb[ls * 512 + h * 32 + jj];
    float kbv = wkb[ls * 512 + h * 32 + jj];
    float vbv = wvb[ls * 512 + h * 32 + jj];
    int wrow = tid >> 3, wcol = (tid << 2) & 31;   // float4 #tid = (row, col)
    float4 pq = *(const float4*)(wqw + (size_t)ls * 16384 + h * 1024 + tid * 4);
    float4 pk = *(const float4*)(wkw + (size_t)ls * 16384 + h * 1024 + tid * 4);
    float4 pv = *(const float4*)(wvw + (size_t)ls * 16384 + h * 1024 + tid * 4);
    float4 p1 = *(const float4*)(l1w + (size_t)ls * 16384 + h * 32 + wrow * 512 + wcol);

    // ---- LN stats from registers ----
    {
        float s1 = av0 + av1 + av2;
        float s2 = av0 * av0 + av1 * av1 + av2 * av2;
        #pragma unroll
        for (int off = 32; off; off >>= 1) { s1 += __shfl_down(s1, off, 64); s2 += __shfl_down(s2, off, 64); }
        if ((tid & 63) == 0) { red[(tid >> 6) * 2] = s1; red[(tid >> 6) * 2 + 1] = s2; }
    }
    __syncthreads();

    float mu, rs;
    {
        float t1 = red[0] + red[2] + red[4] + red[6];
        float t2 = red[1] + red[3] + red[5] + red[7];
        mu = t1 * (1.f / 768.f);
        float var = t2 * (1.f / 768.f) - mu * mu;
        rs = rsqrtf(var + EPS);
    }

    // ---- LN apply from registers ----
    {
        float zn = (av0 - mu) * rs;
        xn[tid] = zn * gx0 + bx0;           yn[tid] = zn * gy0 + by0;
        zn = (av1 - mu) * rs;
        xn[tid + 256] = zn * gx1 + bx1;     yn[tid + 256] = zn * gy1 + by1;
        zn = (av2 - mu) * rs;
        xn[tid + 512] = zn * gx2 + bx2;     yn[tid + 512] = zn * gy2 + by2;
    }
    // ---- stage weights to LDS (padded rows: stride 36 floats) ----
    *(float4*)(wqs + wrow * 36 + wcol) = pq;
    *(float4*)(wks + wrow * 36 + wcol) = pk;
    *(float4*)(wvs + wrow * 36 + wcol) = pv;
    *(float4*)(w1s + wrow * 36 + wcol) = p1;
    __syncthreads();

    // ---- QKV from LDS (weight row hoisted per matrix) ----
    {
        float4 wf[8];
        #pragma unroll
        for (int c4 = 0; c4 < 8; c4++) wf[c4] = *(const float4*)(wqs + jj * 36 + c4 * 4);
        #pragma unroll
        for (int ri = 0; ri < 3; ri++) {
            int r = rb + ri * 8;
            const float4* xr = (const float4*)(xn + r * 32);
            float acc = qbv;
            #pragma unroll
            for (int c4 = 0; c4 < 8; c4++) acc += dot4(xr[c4], wf[c4]);
            q[r * 32 + jj] = acc;
        }
    }
    {
        float4 wf[8];
        #pragma unroll
        for (int c4 = 0; c4 < 8; c4++) wf[c4] = *(const float4*)(wks + jj * 36 + c4 * 4);
        #pragma unroll
        for (int ri = 0; ri < 3; ri++) {
            int r = rb + ri * 8;
            const float4* yr = (const float4*)(yn + r * 32);
            float acc = kbv;
            #pragma unroll
            for (int c4 = 0; c4 < 8; c4++) acc += dot4(yr[c4], wf[c4]);
            kk[r * 32 + jj] = acc;
        }
    }
    {
        float4 wf[8];
        #pragma unroll
        for (int c4 = 0; c4 < 8; c4++) wf[c4] = *(const float4*)(wvs + jj * 36 + c4 * 4);
        #pragma unroll
        for (int ri = 0; ri < 3; ri++) {
            int r = rb + ri * 8;
            const float4* yr = (const float4*)(yn + r * 32);
            float acc = vbv;
            #pragma unroll
            for (int c4 = 0; c4 < 8; c4++) acc += dot4(yr[c4], wf[c4]);
            vv[r * 32 + jj] = acc;
        }
    }
    __syncthreads();

    // ---- scores 24x24 (no softmax) ----
    for (int idx = tid; idx < 576; idx += 256) {
        int r = idx / 24, j = idx - r * 24;
        const float4* qr = (const float4*)(q + r * 32);
        const float4* kr = (const float4*)(kk + j * 32);
        float acc = 0.f;
        #pragma unroll
        for (int c4 = 0; c4 < 8; c4++) acc += dot4(qr[c4], kr[c4]);
        sc[idx] = acc * 0.17677669529663687f;   // 1/sqrt(32)
    }
    __syncthreads();

    // ---- o = sc @ v (24x32) ----
    for (int idx = tid; idx < 768; idx += 256) {
        int r = idx >> 5, c = idx & 31;
        const float* sr = sc + r * 24;
        float acc = 0.f;
        #pragma unroll
        for (int j = 0; j < 24; j++) acc += sr[j] * vv[j * 32 + c];
        oo[idx] = acc;
    }
    __syncthreads();

    // ---- xpart = o_h @ w1_h^T (w1 row from LDS) ----
    float* xp = xpart + (s * 16 + h) * 768;
    {
        float4 wf[8];
        #pragma unroll
        for (int c4 = 0; c4 < 8; c4++) wf[c4] = *(const float4*)(w1s + jj * 36 + c4 * 4);
        #pragma unroll
        for (int ri = 0; ri < 3; ri++) {
            int r = rb + ri * 8;
            const float4* orow = (const float4*)(oo + r * 32);
            float acc = 0.f;
            #pragma unroll
            for (int c4 = 0; c4 < 8; c4++) acc += dot4(orow[c4], wf[c4]);
            xp[r * 32 + jj] = acc;
        }
    }
}

// ---------------- K2: r-split FFN, 144 blocks x 256 threads, weights prefetched ----------------
__global__ __launch_bounds__(256) void k_ffn(
    const float* __restrict__ xm1, const float* __restrict__ xm2,
    const float* __restrict__ xpart,
    const float* __restrict__ l1b,
    const float* __restrict__ lnfg, const float* __restrict__ lnfb,
    const float* __restrict__ l2w, const float* __restrict__ l2b,
    const float* __restrict__ l3w, const float* __restrict__ l3b,
    float* __restrict__ out_m1, float* __restrict__ out_m2,
    float* __restrict__ outp, int i1, int i2, int l)
{
    int s = blockIdx.x / 12, rg = blockIdx.x % 12;
    int r0 = rg * 2;
    int tid = threadIdx.x;
    int ls = l * S + s;
    int jj = tid & 31;
    __shared__ float x[768], hn2[64], g2[256];
    __shared__ float red[16];
    __shared__ float w2s[4608];    // [128][36] padded
    __shared__ float w3s[4224];    // [32][132] padded

    // ---- prefetch weights + biases + LN params ----
    float4 pw2[4], pw3[4];
    const float4* w2g = (const float4*)(l2w + (size_t)ls * 4096);
    const float4* w3g = (const float4*)(l3w + (size_t)ls * 4096);
    #pragma unroll
    for (int k = 0; k < 4; k++) { pw2[k] = w2g[tid + k * 256]; pw3[k] = w3g[tid + k * 256]; }
    float b1v = l1b[ls * 32 + jj];
    float b2v = l2b[ls * 128 + (tid & 127)];
    float b3v = l3b[ls * 32 + ((tid >> 2) & 31)];
    int idxl = (r0 + (tid >> 5)) * 32 + jj;      // valid for tid < 64
    float lg = 0.f, lb = 0.f;
    if (tid < 64) { lg = lnfg[ls * 768 + idxl]; lb = lnfb[ls * 768 + idxl]; }

    // ---- x = a + b1 + sum of 16 head partials, LN stats fused ----
    {
        float s1 = 0.f, s2 = 0.f;
        for (int idx = tid; idx < 768; idx += 256) {
            int r = idx >> 5;
            float av = (r < S) ? xm1[s * 384 + r * 32 + jj]
                               : xm2[(r - S) * 384 + s * 32 + jj];
            float acc = av + b1v;
            const float* xp = xpart + s * 16 * 768 + idx;
            #pragma unroll
            for (int hh = 0; hh < 16; hh++) acc += xp[hh * 768];
            x[idx] = acc;
            s1 += acc; s2 += acc * acc;
        }
        #pragma unroll
        for (int off = 32; off; off >>= 1) { s1 += __shfl_down(s1, off, 64); s2 += __shfl_down(s2, off, 64); }
        if ((tid & 63) == 0) { red[(tid >> 6) * 2] = s1; red[(tid >> 6) * 2 + 1] = s2; }
    }
    __syncthreads();

    float mu, rs;
    {
        float t1 = red[0] + red[2] + red[4] + red[6];
        float t2 = red[1] + red[3] + red[5] + red[7];
        mu = t1 * (1.f / 768.f);
        float var = t2 * (1.f / 768.f) - mu * mu;
        rs = rsqrtf(var + EPS);
    }

    // ---- LN apply for own 2 rows (prefetched gains) ----
    if (tid < 64) hn2[tid] = (x[idxl] - mu) * rs * lg + lb;

    // ---- stage W2/W3 to LDS (padded rows) ----
    #pragma unroll
    for (int k = 0; k < 4; k++) {
        int e = tid + k * 256;
        *(float4*)(w2s + (e >> 3) * 36 + ((e << 2) & 31)) = pw2[k];
        *(float4*)(w3s + (e >> 5) * 132 + ((e << 2) & 127)) = pw3[k];
    }
    __syncthreads();

    // ---- g2 = gelu(hn2 @ W2^T + b2): 2 rows x 128 dots, 1/thread ----
    {
        int rr = tid >> 7, u = tid & 127;
        const float4* hr = (const float4*)(hn2 + rr * 32);
        float acc = b2v;
        #pragma unroll
        for (int c4 = 0; c4 < 8; c4++) acc += dot4(hr[c4], *(const float4*)(w2s + u * 36 + c4 * 4));
        g2[rr * 128 + u] = acc * 0.5f * (1.f + erff(acc * 0.70710678118654752f));
    }
    __syncthreads();

    // ---- out = x + g2 @ W3^T + b3 for own 2 rows (4-way u-split per output) ----
    {
        int oi = tid >> 2, qq = tid & 3;     // 64 outputs x 4 lanes
        int rr = oi >> 5, j = oi & 31;
        int r = r0 + rr;
        const float4* gr = (const float4*)(g2 + rr * 128);
        float p = 0.f;
        #pragma unroll
        for (int u4 = qq * 8; u4 < qq * 8 + 8; u4++) p += dot4(gr[u4], *(const float4*)(w3s + j * 132 + u4 * 4));
        p += __shfl_down(p, 2, 4);
        p += __shfl_down(p, 1, 4);
        if (qq == 0) {
            float val = x[r * 32 + j] + b3v + p;
            if (r < S) {
                out_m1[s * 384 + r * 32 + j] = val;
                if (i1 >= 0) outp[((s * 3 + i1) * 12 + r) * 32 + j] = val;
            } else {
                out_m2[s * 384 + (r - S) * 32 + j] = val;
                if (i2 >= 0) outp[((s * 3 + i2) * 12 + (r - S)) * 32 + j] = val;
            }
        }
    }
}

extern "C" void kernel_launch(void* const* d_in, const int* in_sizes, int n_in,
                              void* d_out, int out_size, void* d_ws, size_t ws_size,
                              hipStream_t stream) {
    const float* input_t = (const float*)d_in[0];
    const float* input_s = (const float*)d_in[1];
    const float* s2g_w   = (const float*)d_in[2];
    const float* s2g_b   = (const float*)d_in[3];
    const float* g2g_w   = (const float*)d_in[4];
    const float* g2g_b   = (const float*)d_in[5];
    const float* lnx_g   = (const float*)d_in[6];
    const float* lnx_b   = (const float*)d_in[7];
    const float* lny_g   = (const float*)d_in[8];
    const float* lny_b   = (const float*)d_in[9];
    const float* lnf_g   = (const float*)d_in[10];
    const float* lnf_b   = (const float*)d_in[11];
    const float* wq_w    = (const float*)d_in[12];
    const float* wq_b    = (const float*)d_in[13];
    const float* wk_w    = (const float*)d_in[14];
    const float* wk_b    = (const float*)d_in[15];
    const float* wv_w    = (const float*)d_in[16];
    const float* wv_b    = (const float*)d_in[17];
    const float* l1_w    = (const float*)d_in[18];
    const float* l1_b    = (const float*)d_in[19];
    const float* l2_w    = (const float*)d_in[20];
    const float* l2_b    = (const float*)d_in[21];
    const float* l3_w    = (const float*)d_in[22];
    const float* l3_b    = (const float*)d_in[23];

    float* ws = (float*)d_ws;
    float* gi    = ws;                       // 3*12240 = 36720
    float* xbuf  = ws + 36720;               // 3*2*4608 = 27648
    float* xpart = ws + 36720 + 27648;       // 12*16*768 = 147456
    float* outp  = (float*)d_out;

    k_prep<<<144, 256, 0, stream>>>(input_t, input_s, s2g_w, s2g_b, gi);
    k_g2g<<<3456, 256, 0, stream>>>(g2g_w, g2g_b, gi, xbuf);

    int par[3] = {0, 0, 0};
    const int pairs[3][2] = {{0, 1}, {2, 0}, {1, 2}};
    for (int l = 0; l < 8; l++) {
        for (int pp = 0; pp < 3; pp++) {
            int m1 = pairs[pp][0], m2 = pairs[pp][1];
            float* in1  = xbuf + m1 * 9216 + par[m1] * 4608;
            float* in2  = xbuf + m2 * 9216 + par[m2] * 4608;
            float* out1 = xbuf + m1 * 9216 + (1 - par[m1]) * 4608;
            float* out2 = xbuf + m2 * 9216 + (1 - par[m2]) * 4608;
            int i1 = -1, i2 = -1;
            if (l == 7 && pp == 1) i2 = 0;
            if (l == 7 && pp == 2) { i1 = 1; i2 = 2; }
            k_attn<<<192, 256, 0, stream>>>(in1, in2,
                lnx_g, lnx_b, lny_g, lny_b,
                wq_w, wq_b, wk_w, wk_b, wv_w, wv_b,
                l1_w, xpart, l);
            k_ffn<<<144, 256, 0, stream>>>(in1, in2, xpart, l1_b,
                lnf_g, lnf_b, l2_w, l2_b, l3_w, l3_b,
                out1, out2, outp, i1, i2, l);
            par[m1] ^= 1; par[m2] ^= 1;
        }
    }
}

// Round 10
// 543.220 us; speedup vs baseline: 2.4674x; 1.0079x over previous
//
#include <hip/hip_runtime.h>
#include <hip/hip_bf16.h>
#include <math.h>

// Sizes
#define S 12
#define C 32
#define T 7
#define GIN 12240         // S*S*(T*S+1)
#define GOUT 4608         // S*S*C
#define EPS 1e-5f

__device__ __forceinline__ float dot4(float4 a, float4 b) {
    return a.x * b.x + a.y * b.y + a.z * b.z + a.w * b.w;
}

// ---------------- prep: build gi[3][12240] ----------------
__global__ __launch_bounds__(256) void k_prep(
    const float* __restrict__ it, const float* __restrict__ is_,
    const float* __restrict__ s2w, const float* __restrict__ s2b,
    float* __restrict__ gi)
{
    int idx = blockIdx.x * 256 + threadIdx.x;
    if (idx >= 3 * GIN) return;
    int i = idx / GIN, rem = idx % GIN;
    int ab = rem / 85, e = rem % 85;
    int a = ab / S, b = ab % S;
    float val;
    if (e < 84) {
        int k = e / T, t = e % T;
        int x, y, z;
        if (i == 0)      { x = a; y = b; z = k; }
        else if (i == 1) { x = b; y = k; z = a; }
        else             { x = k; y = a; z = b; }
        val = it[((t * S + x) * S + y) * S + z];
    } else {
        float acc = s2b[i * 144 + ab];
        const float* wr = s2w + (i * 144 + ab) * 8;
        #pragma unroll
        for (int u = 0; u < 8; u++) acc += wr[u] * is_[u];
        val = acc;
    }
    gi[idx] = val;
}

// ---------------- g2g: x[i] = W[i] @ gi[i] + b[i], one wave per row ----------------
__global__ __launch_bounds__(256) void k_g2g(
    const float* __restrict__ W, const float* __restrict__ gb,
    const float* __restrict__ gi, float* __restrict__ xbuf)
{
    int wave = threadIdx.x >> 6;
    int lane = threadIdx.x & 63;
    int r = blockIdx.x * 4 + wave;          // 0..13823
    int i = r / GOUT, rr = r % GOUT;
    const float4* Wr = reinterpret_cast<const float4*>(W + (size_t)r * GIN);
    const float4* gv = reinterpret_cast<const float4*>(gi + i * GIN);
    float acc = 0.f;
    for (int k = lane; k < GIN / 4; k += 64) {
        float4 w4 = Wr[k];
        float4 g4 = gv[k];
        acc += w4.x * g4.x + w4.y * g4.y + w4.z * g4.z + w4.w * g4.w;
    }
    #pragma unroll
    for (int off = 32; off; off >>= 1) acc += __shfl_down(acc, off, 64);
    if (lane == 0) xbuf[i * (2 * GOUT) + rr] = acc + gb[r];   // parity 0
}

// ---------------- K1: per (slice, head): LN + QKV + scores + O + W1 partial ----------------
// R9 body + q/kk rows padded to stride 36 (144 B): scores-phase ds_read_b128
// goes from ~24-way bank conflict (all j*128-byte rows alias banks 0..3) to ~3-way.
__global__ __launch_bounds__(256) void k_attn(
    const float* __restrict__ xm1, const float* __restrict__ xm2,
    const float* __restrict__ lnxg, const float* __restrict__ lnxb,
    const float* __restrict__ lnyg, const float* __restrict__ lnyb,
    const float* __restrict__ wqw, const float* __restrict__ wqb,
    const float* __restrict__ wkw, const float* __restrict__ wkb,
    const float* __restrict__ wvw, const float* __restrict__ wvb,
    const float* __restrict__ l1w,
    float* __restrict__ xpart, int l)
{
    int s = blockIdx.x >> 4, h = blockIdx.x & 15;
    int tid = threadIdx.x;
    int ls = l * S + s;
    int jj = tid & 31;
    int rb = tid >> 5;                 // base row; owns rows rb, rb+8, rb+16
    __shared__ float xn[768], yn[768], vv[768], oo[768];
    __shared__ float q[864], kk[864];          // 24 rows x stride 36 (padded)
    __shared__ float sc[576];
    __shared__ float red[16];
    __shared__ float wqs[1152], wks[1152], wvs[1152], w1s[1152];   // [32][36] padded

    // ---- a-loads issued FIRST (their wait doesn't include the prefetches) ----
    int r1 = (tid + 256) >> 5;
    float av0 = xm1[s * 384 + rb * 32 + jj];                        // rows 0..7
    float av1 = (r1 < S) ? xm1[s * 384 + r1 * 32 + jj]
                         : xm2[(r1 - S) * 384 + s * 32 + jj];       // rows 8..15
    float av2 = xm2[(((tid + 512) >> 5) - S) * 384 + s * 32 + jj];  // rows 16..23

    // ---- prefetch: LN gains/biases (12 scalars), QKV biases (3), weights (4 x float4) ----
    const float* gx = lnxg + ls * 768; const float* bx = lnxb + ls * 768;
    const float* gy = lnyg + ls * 768; const float* by = lnyb + ls * 768;
    float gx0 = gx[tid], gx1 = gx[tid + 256], gx2 = gx[tid + 512];
    float bx0 = bx[tid], bx1 = bx[tid + 256], bx2 = bx[tid + 512];
    float gy0 = gy[tid], gy1 = gy[tid + 256], gy2 = gy[tid + 512];
    float by0 = by[tid], by1 = by[tid + 256], by2 = by[tid + 512];
    float qbv = wqb[ls * 512 + h * 32 + jj];
    float kbv = wkb[ls * 512 + h * 32 + jj];
    float vbv = wvb[ls * 512 + h * 32 + jj];
    int wrow = tid >> 3, wcol = (tid << 2) & 31;   // float4 #tid = (row, col)
    float4 pq = *(const float4*)(wqw + (size_t)ls * 16384 + h * 1024 + tid * 4);
    float4 pk = *(const float4*)(wkw + (size_t)ls * 16384 + h * 1024 + tid * 4);
    float4 pv = *(const float4*)(wvw + (size_t)ls * 16384 + h * 1024 + tid * 4);
    float4 p1 = *(const float4*)(l1w + (size_t)ls * 16384 + h * 32 + wrow * 512 + wcol);

    // ---- LN stats from registers ----
    {
        float s1 = av0 + av1 + av2;
        float s2 = av0 * av0 + av1 * av1 + av2 * av2;
        #pragma unroll
        for (int off = 32; off; off >>= 1) { s1 += __shfl_down(s1, off, 64); s2 += __shfl_down(s2, off, 64); }
        if ((tid & 63) == 0) { red[(tid >> 6) * 2] = s1; red[(tid >> 6) * 2 + 1] = s2; }
    }
    __syncthreads();

    float mu, rs;
    {
        float t1 = red[0] + red[2] + red[4] + red[6];
        float t2 = red[1] + red[3] + red[5] + red[7];
        mu = t1 * (1.f / 768.f);
        float var = t2 * (1.f / 768.f) - mu * mu;
        rs = rsqrtf(var + EPS);
    }

    // ---- LN apply from registers ----
    {
        float zn = (av0 - mu) * rs;
        xn[tid] = zn * gx0 + bx0;           yn[tid] = zn * gy0 + by0;
        zn = (av1 - mu) * rs;
        xn[tid + 256] = zn * gx1 + bx1;     yn[tid + 256] = zn * gy1 + by1;
        zn = (av2 - mu) * rs;
        xn[tid + 512] = zn * gx2 + bx2;     yn[tid + 512] = zn * gy2 + by2;
    }
    // ---- stage weights to LDS (padded rows: stride 36 floats) ----
    *(float4*)(wqs + wrow * 36 + wcol) = pq;
    *(float4*)(wks + wrow * 36 + wcol) = pk;
    *(float4*)(wvs + wrow * 36 + wcol) = pv;
    *(float4*)(w1s + wrow * 36 + wcol) = p1;
    __syncthreads();

    // ---- QKV from LDS (weight row hoisted per matrix) ----
    {
        float4 wf[8];
        #pragma unroll
        for (int c4 = 0; c4 < 8; c4++) wf[c4] = *(const float4*)(wqs + jj * 36 + c4 * 4);
        #pragma unroll
        for (int ri = 0; ri < 3; ri++) {
            int r = rb + ri * 8;
            const float4* xr = (const float4*)(xn + r * 32);
            float acc = qbv;
            #pragma unroll
            for (int c4 = 0; c4 < 8; c4++) acc += dot4(xr[c4], wf[c4]);
            q[r * 36 + jj] = acc;
        }
    }
    {
        float4 wf[8];
        #pragma unroll
        for (int c4 = 0; c4 < 8; c4++) wf[c4] = *(const float4*)(wks + jj * 36 + c4 * 4);
        #pragma unroll
        for (int ri = 0; ri < 3; ri++) {
            int r = rb + ri * 8;
            const float4* yr = (const float4*)(yn + r * 32);
            float acc = kbv;
            #pragma unroll
            for (int c4 = 0; c4 < 8; c4++) acc += dot4(yr[c4], wf[c4]);
            kk[r * 36 + jj] = acc;
        }
    }
    {
        float4 wf[8];
        #pragma unroll
        for (int c4 = 0; c4 < 8; c4++) wf[c4] = *(const float4*)(wvs + jj * 36 + c4 * 4);
        #pragma unroll
        for (int ri = 0; ri < 3; ri++) {
            int r = rb + ri * 8;
            const float4* yr = (const float4*)(yn + r * 32);
            float acc = vbv;
            #pragma unroll
            for (int c4 = 0; c4 < 8; c4++) acc += dot4(yr[c4], wf[c4]);
            vv[r * 32 + jj] = acc;
        }
    }
    __syncthreads();

    // ---- scores 24x24 (no softmax); q/kk stride 36 -> ~3-way banks ----
    for (int idx = tid; idx < 576; idx += 256) {
        int r = idx / 24, j = idx - r * 24;
        const float4* qr = (const float4*)(q + r * 36);
        const float4* kr = (const float4*)(kk + j * 36);
        float acc = 0.f;
        #pragma unroll
        for (int c4 = 0; c4 < 8; c4++) acc += dot4(qr[c4], kr[c4]);
        sc[idx] = acc * 0.17677669529663687f;   // 1/sqrt(32)
    }
    __syncthreads();

    // ---- o = sc @ v (24x32) ----
    for (int idx = tid; idx < 768; idx += 256) {
        int r = idx >> 5, c = idx & 31;
        const float* sr = sc + r * 24;
        float acc = 0.f;
        #pragma unroll
        for (int j = 0; j < 24; j++) acc += sr[j] * vv[j * 32 + c];
        oo[idx] = acc;
    }
    __syncthreads();

    // ---- xpart = o_h @ w1_h^T (w1 row from LDS) ----
    float* xp = xpart + (s * 16 + h) * 768;
    {
        float4 wf[8];
        #pragma unroll
        for (int c4 = 0; c4 < 8; c4++) wf[c4] = *(const float4*)(w1s + jj * 36 + c4 * 4);
        #pragma unroll
        for (int ri = 0; ri < 3; ri++) {
            int r = rb + ri * 8;
            const float4* orow = (const float4*)(oo + r * 32);
            float acc = 0.f;
            #pragma unroll
            for (int c4 = 0; c4 < 8; c4++) acc += dot4(orow[c4], wf[c4]);
            xp[r * 32 + jj] = acc;
        }
    }
}

// ---------------- K2: r-split FFN, 144 blocks x 256 threads, weights prefetched ----------------
__global__ __launch_bounds__(256) void k_ffn(
    const float* __restrict__ xm1, const float* __restrict__ xm2,
    const float* __restrict__ xpart,
    const float* __restrict__ l1b,
    const float* __restrict__ lnfg, const float* __restrict__ lnfb,
    const float* __restrict__ l2w, const float* __restrict__ l2b,
    const float* __restrict__ l3w, const float* __restrict__ l3b,
    float* __restrict__ out_m1, float* __restrict__ out_m2,
    float* __restrict__ outp, int i1, int i2, int l)
{
    int s = blockIdx.x / 12, rg = blockIdx.x % 12;
    int r0 = rg * 2;
    int tid = threadIdx.x;
    int ls = l * S + s;
    int jj = tid & 31;
    __shared__ float x[768], hn2[64], g2[256];
    __shared__ float red[16];
    __shared__ float w2s[4608];    // [128][36] padded
    __shared__ float w3s[4224];    // [32][132] padded

    // ---- prefetch weights + biases + LN params ----
    float4 pw2[4], pw3[4];
    const float4* w2g = (const float4*)(l2w + (size_t)ls * 4096);
    const float4* w3g = (const float4*)(l3w + (size_t)ls * 4096);
    #pragma unroll
    for (int k = 0; k < 4; k++) { pw2[k] = w2g[tid + k * 256]; pw3[k] = w3g[tid + k * 256]; }
    float b1v = l1b[ls * 32 + jj];
    float b2v = l2b[ls * 128 + (tid & 127)];
    float b3v = l3b[ls * 32 + ((tid >> 2) & 31)];
    int idxl = (r0 + (tid >> 5)) * 32 + jj;      // valid for tid < 64
    float lg = 0.f, lb = 0.f;
    if (tid < 64) { lg = lnfg[ls * 768 + idxl]; lb = lnfb[ls * 768 + idxl]; }

    // ---- x = a + b1 + sum of 16 head partials, LN stats fused ----
    {
        float s1 = 0.f, s2 = 0.f;
        for (int idx = tid; idx < 768; idx += 256) {
            int r = idx >> 5;
            float av = (r < S) ? xm1[s * 384 + r * 32 + jj]
                               : xm2[(r - S) * 384 + s * 32 + jj];
            float acc = av + b1v;
            const float* xp = xpart + s * 16 * 768 + idx;
            #pragma unroll
            for (int hh = 0; hh < 16; hh++) acc += xp[hh * 768];
            x[idx] = acc;
            s1 += acc; s2 += acc * acc;
        }
        #pragma unroll
        for (int off = 32; off; off >>= 1) { s1 += __shfl_down(s1, off, 64); s2 += __shfl_down(s2, off, 64); }
        if ((tid & 63) == 0) { red[(tid >> 6) * 2] = s1; red[(tid >> 6) * 2 + 1] = s2; }
    }
    __syncthreads();

    float mu, rs;
    {
        float t1 = red[0] + red[2] + red[4] + red[6];
        float t2 = red[1] + red[3] + red[5] + red[7];
        mu = t1 * (1.f / 768.f);
        float var = t2 * (1.f / 768.f) - mu * mu;
        rs = rsqrtf(var + EPS);
    }

    // ---- LN apply for own 2 rows (prefetched gains) ----
    if (tid < 64) hn2[tid] = (x[idxl] - mu) * rs * lg + lb;

    // ---- stage W2/W3 to LDS (padded rows) ----
    #pragma unroll
    for (int k = 0; k < 4; k++) {
        int e = tid + k * 256;
        *(float4*)(w2s + (e >> 3) * 36 + ((e << 2) & 31)) = pw2[k];
        *(float4*)(w3s + (e >> 5) * 132 + ((e << 2) & 127)) = pw3[k];
    }
    __syncthreads();

    // ---- g2 = gelu(hn2 @ W2^T + b2): 2 rows x 128 dots, 1/thread ----
    {
        int rr = tid >> 7, u = tid & 127;
        const float4* hr = (const float4*)(hn2 + rr * 32);
        float acc = b2v;
        #pragma unroll
        for (int c4 = 0; c4 < 8; c4++) acc += dot4(hr[c4], *(const float4*)(w2s + u * 36 + c4 * 4));
        g2[rr * 128 + u] = acc * 0.5f * (1.f + erff(acc * 0.70710678118654752f));
    }
    __syncthreads();

    // ---- out = x + g2 @ W3^T + b3 for own 2 rows (4-way u-split per output) ----
    {
        int oi = tid >> 2, qq = tid & 3;     // 64 outputs x 4 lanes
        int rr = oi >> 5, j = oi & 31;
        int r = r0 + rr;
        const float4* gr = (const float4*)(g2 + rr * 128);
        float p = 0.f;
        #pragma unroll
        for (int u4 = qq * 8; u4 < qq * 8 + 8; u4++) p += dot4(gr[u4], *(const float4*)(w3s + j * 132 + u4 * 4));
        p += __shfl_down(p, 2, 4);
        p += __shfl_down(p, 1, 4);
        if (qq == 0) {
            float val = x[r * 32 + j] + b3v + p;
            if (r < S) {
                out_m1[s * 384 + r * 32 + j] = val;
                if (i1 >= 0) outp[((s * 3 + i1) * 12 + r) * 32 + j] = val;
            } else {
                out_m2[s * 384 + (r - S) * 32 + j] = val;
                if (i2 >= 0) outp[((s * 3 + i2) * 12 + (r - S)) * 32 + j] = val;
            }
        }
    }
}

extern "C" void kernel_launch(void* const* d_in, const int* in_sizes, int n_in,
                              void* d_out, int out_size, void* d_ws, size_t ws_size,
                              hipStream_t stream) {
    const float* input_t = (const float*)d_in[0];
    const float* input_s = (const float*)d_in[1];
    const float* s2g_w   = (const float*)d_in[2];
    const float* s2g_b   = (const float*)d_in[3];
    const float* g2g_w   = (const float*)d_in[4];
    const float* g2g_b   = (const float*)d_in[5];
    const float* lnx_g   = (const float*)d_in[6];
    const float* lnx_b   = (const float*)d_in[7];
    const float* lny_g   = (const float*)d_in[8];
    const float* lny_b   = (const float*)d_in[9];
    const float* lnf_g   = (const float*)d_in[10];
    const float* lnf_b   = (const float*)d_in[11];
    const float* wq_w    = (const float*)d_in[12];
    const float* wq_b    = (const float*)d_in[13];
    const float* wk_w    = (const float*)d_in[14];
    const float* wk_b    = (const float*)d_in[15];
    const float* wv_w    = (const float*)d_in[16];
    const float* wv_b    = (const float*)d_in[17];
    const float* l1_w    = (const float*)d_in[18];
    const float* l1_b    = (const float*)d_in[19];
    const float* l2_w    = (const float*)d_in[20];
    const float* l2_b    = (const float*)d_in[21];
    const float* l3_w    = (const float*)d_in[22];
    const float* l3_b    = (const float*)d_in[23];

    float* ws = (float*)d_ws;
    float* gi    = ws;                       // 3*12240 = 36720
    float* xbuf  = ws + 36720;               // 3*2*4608 = 27648
    float* xpart = ws + 36720 + 27648;       // 12*16*768 = 147456
    float* outp  = (float*)d_out;

    k_prep<<<144, 256, 0, stream>>>(input_t, input_s, s2g_w, s2g_b, gi);
    k_g2g<<<3456, 256, 0, stream>>>(g2g_w, g2g_b, gi, xbuf);

    int par[3] = {0, 0, 0};
    const int pairs[3][2] = {{0, 1}, {2, 0}, {1, 2}};
    for (int l = 0; l < 8; l++) {
        for (int pp = 0; pp < 3; pp++) {
            int m1 = pairs[pp][0], m2 = pairs[pp][1];
            float* in1  = xbuf + m1 * 9216 + par[m1] * 4608;
            float* in2  = xbuf + m2 * 9216 + par[m2] * 4608;
            float* out1 = xbuf + m1 * 9216 + (1 - par[m1]) * 4608;
            float* out2 = xbuf + m2 * 9216 + (1 - par[m2]) * 4608;
            int i1 = -1, i2 = -1;
            if (l == 7 && pp == 1) i2 = 0;
            if (l == 7 && pp == 2) { i1 = 1; i2 = 2; }
            k_attn<<<192, 256, 0, stream>>>(in1, in2,
                lnx_g, lnx_b, lny_g, lny_b,
                wq_w, wq_b, wk_w, wk_b, wv_w, wv_b,
                l1_w, xpart, l);
            k_ffn<<<144, 256, 0, stream>>>(in1, in2, xpart, l1_b,
                lnf_g, lnf_b, l2_w, l2_b, l3_w, l3_b,
                out1, out2, outp, i1, i2, l);
            par[m1] ^= 1; par[m2] ^= 1;
        }
    }
}

// Round 11
// 515.807 us; speedup vs baseline: 2.5986x; 1.0531x over previous
//
#include <hip/hip_runtime.h>
#include <hip/hip_bf16.h>
#include <math.h>

// Sizes
#define S 12
#define C 32
#define T 7
#define GIN 12240         // S*S*(T*S+1)
#define GOUT 4608         // S*S*C
#define EPS 1e-5f

__device__ __forceinline__ float dot4(float4 a, float4 b) {
    return a.x * b.x + a.y * b.y + a.z * b.z + a.w * b.w;
}

// ---------------- prep: build gi[3][12240] ----------------
__global__ __launch_bounds__(256) void k_prep(
    const float* __restrict__ it, const float* __restrict__ is_,
    const float* __restrict__ s2w, const float* __restrict__ s2b,
    float* __restrict__ gi)
{
    int idx = blockIdx.x * 256 + threadIdx.x;
    if (idx >= 3 * GIN) return;
    int i = idx / GIN, rem = idx % GIN;
    int ab = rem / 85, e = rem % 85;
    int a = ab / S, b = ab % S;
    float val;
    if (e < 84) {
        int k = e / T, t = e % T;
        int x, y, z;
        if (i == 0)      { x = a; y = b; z = k; }
        else if (i == 1) { x = b; y = k; z = a; }
        else             { x = k; y = a; z = b; }
        val = it[((t * S + x) * S + y) * S + z];
    } else {
        float acc = s2b[i * 144 + ab];
        const float* wr = s2w + (i * 144 + ab) * 8;
        #pragma unroll
        for (int u = 0; u < 8; u++) acc += wr[u] * is_[u];
        val = acc;
    }
    gi[idx] = val;
}

// ---------------- g2g: x[i] = W[i] @ gi[i] + b[i], one wave per row ----------------
__global__ __launch_bounds__(256) void k_g2g(
    const float* __restrict__ W, const float* __restrict__ gb,
    const float* __restrict__ gi, float* __restrict__ xbuf)
{
    int wave = threadIdx.x >> 6;
    int lane = threadIdx.x & 63;
    int r = blockIdx.x * 4 + wave;          // 0..13823
    int i = r / GOUT, rr = r % GOUT;
    const float4* Wr = reinterpret_cast<const float4*>(W + (size_t)r * GIN);
    const float4* gv = reinterpret_cast<const float4*>(gi + i * GIN);
    float acc = 0.f;
    for (int k = lane; k < GIN / 4; k += 64) {
        float4 w4 = Wr[k];
        float4 g4 = gv[k];
        acc += w4.x * g4.x + w4.y * g4.y + w4.z * g4.z + w4.w * g4.w;
    }
    #pragma unroll
    for (int off = 32; off; off >>= 1) acc += __shfl_down(acc, off, 64);
    if (lane == 0) xbuf[i * (2 * GOUT) + rr] = acc + gb[r];   // parity 0
}

// ---------------- K1: per (slice, head): LN + QKV + scores + O + W1 partial ----------------
// R10 body with (a) fused Q/K/V matmul (one pass over rows: 72 vs 96 LDS
// b128 reads/thread, identical per-output summation order) and (b) per-wave
// row-ownership for scores->o->W1 (wave w owns rows 6w..6w+5; both
// inter-phase barriers removed; 5 -> 3 barriers).
__global__ __launch_bounds__(256) void k_attn(
    const float* __restrict__ xm1, const float* __restrict__ xm2,
    const float* __restrict__ lnxg, const float* __restrict__ lnxb,
    const float* __restrict__ lnyg, const float* __restrict__ lnyb,
    const float* __restrict__ wqw, const float* __restrict__ wqb,
    const float* __restrict__ wkw, const float* __restrict__ wkb,
    const float* __restrict__ wvw, const float* __restrict__ wvb,
    const float* __restrict__ l1w,
    float* __restrict__ xpart, int l)
{
    int s = blockIdx.x >> 4, h = blockIdx.x & 15;
    int tid = threadIdx.x;
    int ls = l * S + s;
    int jj = tid & 31;
    int rb = tid >> 5;                 // base row; owns rows rb, rb+8, rb+16
    __shared__ float xn[768], yn[768], vv[768], oo[768];
    __shared__ float q[864], kk[864];          // 24 rows x stride 36 (padded)
    __shared__ float sc[576];
    __shared__ float red[16];
    __shared__ float wqs[1152], wks[1152], wvs[1152], w1s[1152];   // [32][36] padded

    // ---- a-loads issued FIRST (their wait doesn't include the prefetches) ----
    int r1 = (tid + 256) >> 5;
    float av0 = xm1[s * 384 + rb * 32 + jj];                        // rows 0..7
    float av1 = (r1 < S) ? xm1[s * 384 + r1 * 32 + jj]
                         : xm2[(r1 - S) * 384 + s * 32 + jj];       // rows 8..15
    float av2 = xm2[(((tid + 512) >> 5) - S) * 384 + s * 32 + jj];  // rows 16..23

    // ---- prefetch: LN gains/biases, QKV biases, weights ----
    const float* gx = lnxg + ls * 768; const float* bx = lnxb + ls * 768;
    const float* gy = lnyg + ls * 768; const float* by = lnyb + ls * 768;
    float gx0 = gx[tid], gx1 = gx[tid + 256], gx2 = gx[tid + 512];
    float bx0 = bx[tid], bx1 = bx[tid + 256], bx2 = bx[tid + 512];
    float gy0 = gy[tid], gy1 = gy[tid + 256], gy2 = gy[tid + 512];
    float by0 = by[tid], by1 = by[tid + 256], by2 = by[tid + 512];
    float qbv = wqb[ls * 512 + h * 32 + jj];
    float kbv = wkb[ls * 512 + h * 32 + jj];
    float vbv = wvb[ls * 512 + h * 32 + jj];
    int wrow = tid >> 3, wcol = (tid << 2) & 31;   // float4 #tid = (row, col)
    float4 pq = *(const float4*)(wqw + (size_t)ls * 16384 + h * 1024 + tid * 4);
    float4 pk = *(const float4*)(wkw + (size_t)ls * 16384 + h * 1024 + tid * 4);
    float4 pv = *(const float4*)(wvw + (size_t)ls * 16384 + h * 1024 + tid * 4);
    float4 p1 = *(const float4*)(l1w + (size_t)ls * 16384 + h * 32 + wrow * 512 + wcol);

    // ---- LN stats from registers ----
    {
        float s1 = av0 + av1 + av2;
        float s2 = av0 * av0 + av1 * av1 + av2 * av2;
        #pragma unroll
        for (int off = 32; off; off >>= 1) { s1 += __shfl_down(s1, off, 64); s2 += __shfl_down(s2, off, 64); }
        if ((tid & 63) == 0) { red[(tid >> 6) * 2] = s1; red[(tid >> 6) * 2 + 1] = s2; }
    }
    __syncthreads();

    float mu, rs;
    {
        float t1 = red[0] + red[2] + red[4] + red[6];
        float t2 = red[1] + red[3] + red[5] + red[7];
        mu = t1 * (1.f / 768.f);
        float var = t2 * (1.f / 768.f) - mu * mu;
        rs = rsqrtf(var + EPS);
    }

    // ---- LN apply from registers + stage weights to LDS ----
    {
        float zn = (av0 - mu) * rs;
        xn[tid] = zn * gx0 + bx0;           yn[tid] = zn * gy0 + by0;
        zn = (av1 - mu) * rs;
        xn[tid + 256] = zn * gx1 + bx1;     yn[tid + 256] = zn * gy1 + by1;
        zn = (av2 - mu) * rs;
        xn[tid + 512] = zn * gx2 + bx2;     yn[tid + 512] = zn * gy2 + by2;
    }
    *(float4*)(wqs + wrow * 36 + wcol) = pq;
    *(float4*)(wks + wrow * 36 + wcol) = pk;
    *(float4*)(wvs + wrow * 36 + wcol) = pv;
    *(float4*)(w1s + wrow * 36 + wcol) = p1;
    __syncthreads();

    // ---- fused QKV: one pass over rows; 9 accumulators ----
    {
        float aq[3], ak[3], av[3];
        #pragma unroll
        for (int ri = 0; ri < 3; ri++) { aq[ri] = qbv; ak[ri] = kbv; av[ri] = vbv; }
        #pragma unroll
        for (int c4 = 0; c4 < 8; c4++) {
            float4 wq4 = *(const float4*)(wqs + jj * 36 + c4 * 4);
            float4 wk4 = *(const float4*)(wks + jj * 36 + c4 * 4);
            float4 wv4 = *(const float4*)(wvs + jj * 36 + c4 * 4);
            #pragma unroll
            for (int ri = 0; ri < 3; ri++) {
                int r = rb + ri * 8;
                float4 xv = *(const float4*)(xn + r * 32 + c4 * 4);
                float4 yv = *(const float4*)(yn + r * 32 + c4 * 4);
                aq[ri] += dot4(xv, wq4);
                ak[ri] += dot4(yv, wk4);
                av[ri] += dot4(yv, wv4);
            }
        }
        #pragma unroll
        for (int ri = 0; ri < 3; ri++) {
            int r = rb + ri * 8;
            q[r * 36 + jj] = aq[ri];
            kk[r * 36 + jj] = ak[ri];
            vv[r * 32 + jj] = av[ri];
        }
    }
    __syncthreads();

    // ---- per-wave fused scores -> o -> W1 (wave w owns rows 6w..6w+5) ----
    int wv = tid >> 6;
    int lane = tid & 63;
    float* xp = xpart + (s * 16 + h) * 768;

    // scores 6x24 for own rows
    for (int idx = lane; idx < 144; idx += 64) {
        int rl = idx / 24, j = idx - rl * 24;
        int r = wv * 6 + rl;
        const float4* qr = (const float4*)(q + r * 36);
        const float4* kr = (const float4*)(kk + j * 36);
        float acc = 0.f;
        #pragma unroll
        for (int c4 = 0; c4 < 8; c4++) acc += dot4(qr[c4], kr[c4]);
        sc[r * 24 + j] = acc * 0.17677669529663687f;   // 1/sqrt(32)
    }
    // o = sc @ v for own rows (same-wave LDS RAW: hardware in-order + lgkmcnt)
    for (int idx = lane; idx < 192; idx += 64) {
        int rl = idx >> 5, c = idx & 31;
        int r = wv * 6 + rl;
        const float* sr = sc + r * 24;
        float acc = 0.f;
        #pragma unroll
        for (int j = 0; j < 24; j++) acc += sr[j] * vv[j * 32 + c];
        oo[r * 32 + c] = acc;
    }
    // xpart = o @ w1^T for own rows
    for (int idx = lane; idx < 192; idx += 64) {
        int rl = idx >> 5, j = idx & 31;
        int r = wv * 6 + rl;
        const float4* orow = (const float4*)(oo + r * 32);
        float acc = 0.f;
        #pragma unroll
        for (int c4 = 0; c4 < 8; c4++) acc += dot4(orow[c4], *(const float4*)(w1s + j * 36 + c4 * 4));
        xp[r * 32 + j] = acc;
    }
}

// ---------------- K2: r-split FFN, 144 blocks x 256 threads, weights prefetched ----------------
__global__ __launch_bounds__(256) void k_ffn(
    const float* __restrict__ xm1, const float* __restrict__ xm2,
    const float* __restrict__ xpart,
    const float* __restrict__ l1b,
    const float* __restrict__ lnfg, const float* __restrict__ lnfb,
    const float* __restrict__ l2w, const float* __restrict__ l2b,
    const float* __restrict__ l3w, const float* __restrict__ l3b,
    float* __restrict__ out_m1, float* __restrict__ out_m2,
    float* __restrict__ outp, int i1, int i2, int l)
{
    int s = blockIdx.x / 12, rg = blockIdx.x % 12;
    int r0 = rg * 2;
    int tid = threadIdx.x;
    int ls = l * S + s;
    int jj = tid & 31;
    __shared__ float x[768], hn2[64], g2[256];
    __shared__ float red[16];
    __shared__ float w2s[4608];    // [128][36] padded
    __shared__ float w3s[4224];    // [32][132] padded

    // ---- prefetch weights + biases + LN params ----
    float4 pw2[4], pw3[4];
    const float4* w2g = (const float4*)(l2w + (size_t)ls * 4096);
    const float4* w3g = (const float4*)(l3w + (size_t)ls * 4096);
    #pragma unroll
    for (int k = 0; k < 4; k++) { pw2[k] = w2g[tid + k * 256]; pw3[k] = w3g[tid + k * 256]; }
    float b1v = l1b[ls * 32 + jj];
    float b2v = l2b[ls * 128 + (tid & 127)];
    float b3v = l3b[ls * 32 + ((tid >> 2) & 31)];
    int idxl = (r0 + (tid >> 5)) * 32 + jj;      // valid for tid < 64
    float lg = 0.f, lb = 0.f;
    if (tid < 64) { lg = lnfg[ls * 768 + idxl]; lb = lnfb[ls * 768 + idxl]; }

    // ---- x = a + b1 + sum of 16 head partials, LN stats fused ----
    {
        float s1 = 0.f, s2 = 0.f;
        for (int idx = tid; idx < 768; idx += 256) {
            int r = idx >> 5;
            float av = (r < S) ? xm1[s * 384 + r * 32 + jj]
                               : xm2[(r - S) * 384 + s * 32 + jj];
            float acc = av + b1v;
            const float* xp = xpart + s * 16 * 768 + idx;
            #pragma unroll
            for (int hh = 0; hh < 16; hh++) acc += xp[hh * 768];
            x[idx] = acc;
            s1 += acc; s2 += acc * acc;
        }
        #pragma unroll
        for (int off = 32; off; off >>= 1) { s1 += __shfl_down(s1, off, 64); s2 += __shfl_down(s2, off, 64); }
        if ((tid & 63) == 0) { red[(tid >> 6) * 2] = s1; red[(tid >> 6) * 2 + 1] = s2; }
    }
    __syncthreads();

    float mu, rs;
    {
        float t1 = red[0] + red[2] + red[4] + red[6];
        float t2 = red[1] + red[3] + red[5] + red[7];
        mu = t1 * (1.f / 768.f);
        float var = t2 * (1.f / 768.f) - mu * mu;
        rs = rsqrtf(var + EPS);
    }

    // ---- LN apply for own 2 rows (prefetched gains) ----
    if (tid < 64) hn2[tid] = (x[idxl] - mu) * rs * lg + lb;

    // ---- stage W2/W3 to LDS (padded rows) ----
    #pragma unroll
    for (int k = 0; k < 4; k++) {
        int e = tid + k * 256;
        *(float4*)(w2s + (e >> 3) * 36 + ((e << 2) & 31)) = pw2[k];
        *(float4*)(w3s + (e >> 5) * 132 + ((e << 2) & 127)) = pw3[k];
    }
    __syncthreads();

    // ---- g2 = gelu(hn2 @ W2^T + b2): 2 rows x 128 dots, 1/thread ----
    {
        int rr = tid >> 7, u = tid & 127;
        const float4* hr = (const float4*)(hn2 + rr * 32);
        float acc = b2v;
        #pragma unroll
        for (int c4 = 0; c4 < 8; c4++) acc += dot4(hr[c4], *(const float4*)(w2s + u * 36 + c4 * 4));
        g2[rr * 128 + u] = acc * 0.5f * (1.f + erff(acc * 0.70710678118654752f));
    }
    __syncthreads();

    // ---- out = x + g2 @ W3^T + b3 for own 2 rows (4-way u-split per output) ----
    {
        int oi = tid >> 2, qq = tid & 3;     // 64 outputs x 4 lanes
        int rr = oi >> 5, j = oi & 31;
        int r = r0 + rr;
        const float4* gr = (const float4*)(g2 + rr * 128);
        float p = 0.f;
        #pragma unroll
        for (int u4 = qq * 8; u4 < qq * 8 + 8; u4++) p += dot4(gr[u4], *(const float4*)(w3s + j * 132 + u4 * 4));
        p += __shfl_down(p, 2, 4);
        p += __shfl_down(p, 1, 4);
        if (qq == 0) {
            float val = x[r * 32 + j] + b3v + p;
            if (r < S) {
                out_m1[s * 384 + r * 32 + j] = val;
                if (i1 >= 0) outp[((s * 3 + i1) * 12 + r) * 32 + j] = val;
            } else {
                out_m2[s * 384 + (r - S) * 32 + j] = val;
                if (i2 >= 0) outp[((s * 3 + i2) * 12 + (r - S)) * 32 + j] = val;
            }
        }
    }
}

extern "C" void kernel_launch(void* const* d_in, const int* in_sizes, int n_in,
                              void* d_out, int out_size, void* d_ws, size_t ws_size,
                              hipStream_t stream) {
    const float* input_t = (const float*)d_in[0];
    const float* input_s = (const float*)d_in[1];
    const float* s2g_w   = (const float*)d_in[2];
    const float* s2g_b   = (const float*)d_in[3];
    const float* g2g_w   = (const float*)d_in[4];
    const float* g2g_b   = (const float*)d_in[5];
    const float* lnx_g   = (const float*)d_in[6];
    const float* lnx_b   = (const float*)d_in[7];
    const float* lny_g   = (const float*)d_in[8];
    const float* lny_b   = (const float*)d_in[9];
    const float* lnf_g   = (const float*)d_in[10];
    const float* lnf_b   = (const float*)d_in[11];
    const float* wq_w    = (const float*)d_in[12];
    const float* wq_b    = (const float*)d_in[13];
    const float* wk_w    = (const float*)d_in[14];
    const float* wk_b    = (const float*)d_in[15];
    const float* wv_w    = (const float*)d_in[16];
    const float* wv_b    = (const float*)d_in[17];
    const float* l1_w    = (const float*)d_in[18];
    const float* l1_b    = (const float*)d_in[19];
    const float* l2_w    = (const float*)d_in[20];
    const float* l2_b    = (const float*)d_in[21];
    const float* l3_w    = (const float*)d_in[22];
    const float* l3_b    = (const float*)d_in[23];

    float* ws = (float*)d_ws;
    float* gi    = ws;                       // 3*12240 = 36720
    float* xbuf  = ws + 36720;               // 3*2*4608 = 27648
    float* xpart = ws + 36720 + 27648;       // 12*16*768 = 147456
    float* outp  = (float*)d_out;

    k_prep<<<144, 256, 0, stream>>>(input_t, input_s, s2g_w, s2g_b, gi);
    k_g2g<<<3456, 256, 0, stream>>>(g2g_w, g2g_b, gi, xbuf);

    int par[3] = {0, 0, 0};
    const int pairs[3][2] = {{0, 1}, {2, 0}, {1, 2}};
    for (int l = 0; l < 8; l++) {
        for (int pp = 0; pp < 3; pp++) {
            int m1 = pairs[pp][0], m2 = pairs[pp][1];
            float* in1  = xbuf + m1 * 9216 + par[m1] * 4608;
            float* in2  = xbuf + m2 * 9216 + par[m2] * 4608;
            float* out1 = xbuf + m1 * 9216 + (1 - par[m1]) * 4608;
            float* out2 = xbuf + m2 * 9216 + (1 - par[m2]) * 4608;
            int i1 = -1, i2 = -1;
            if (l == 7 && pp == 1) i2 = 0;
            if (l == 7 && pp == 2) { i1 = 1; i2 = 2; }
            k_attn<<<192, 256, 0, stream>>>(in1, in2,
                lnx_g, lnx_b, lny_g, lny_b,
                wq_w, wq_b, wk_w, wk_b, wv_w, wv_b,
                l1_w, xpart, l);
            k_ffn<<<144, 256, 0, stream>>>(in1, in2, xpart, l1_b,
                lnf_g, lnf_b, l2_w, l2_b, l3_w, l3_b,
                out1, out2, outp, i1, i2, l);
            par[m1] ^= 1; par[m2] ^= 1;
        }
    }
}

// Round 12
// 514.838 us; speedup vs baseline: 2.6035x; 1.0019x over previous
//
#include <hip/hip_runtime.h>
#include <hip/hip_bf16.h>
#include <math.h>

// Sizes
#define S 12
#define C 32
#define T 7
#define GIN 12240         // S*S*(T*S+1)
#define GOUT 4608         // S*S*C
#define EPS 1e-5f

__device__ __forceinline__ float dot4(float4 a, float4 b) {
    return a.x * b.x + a.y * b.y + a.z * b.z + a.w * b.w;
}

// ---------------- prep: build gi[3][12240] ----------------
__global__ __launch_bounds__(256) void k_prep(
    const float* __restrict__ it, const float* __restrict__ is_,
    const float* __restrict__ s2w, const float* __restrict__ s2b,
    float* __restrict__ gi)
{
    int idx = blockIdx.x * 256 + threadIdx.x;
    if (idx >= 3 * GIN) return;
    int i = idx / GIN, rem = idx % GIN;
    int ab = rem / 85, e = rem % 85;
    int a = ab / S, b = ab % S;
    float val;
    if (e < 84) {
        int k = e / T, t = e % T;
        int x, y, z;
        if (i == 0)      { x = a; y = b; z = k; }
        else if (i == 1) { x = b; y = k; z = a; }
        else             { x = k; y = a; z = b; }
        val = it[((t * S + x) * S + y) * S + z];
    } else {
        float acc = s2b[i * 144 + ab];
        const float* wr = s2w + (i * 144 + ab) * 8;
        #pragma unroll
        for (int u = 0; u < 8; u++) acc += wr[u] * is_[u];
        val = acc;
    }
    gi[idx] = val;
}

// ---------------- g2g: x[i] = W[i] @ gi[i] + b[i], one wave per row ----------------
__global__ __launch_bounds__(256) void k_g2g(
    const float* __restrict__ W, const float* __restrict__ gb,
    const float* __restrict__ gi, float* __restrict__ xbuf)
{
    int wave = threadIdx.x >> 6;
    int lane = threadIdx.x & 63;
    int r = blockIdx.x * 4 + wave;          // 0..13823
    int i = r / GOUT, rr = r % GOUT;
    const float4* Wr = reinterpret_cast<const float4*>(W + (size_t)r * GIN);
    const float4* gv = reinterpret_cast<const float4*>(gi + i * GIN);
    float acc = 0.f;
    for (int k = lane; k < GIN / 4; k += 64) {
        float4 w4 = Wr[k];
        float4 g4 = gv[k];
        acc += w4.x * g4.x + w4.y * g4.y + w4.z * g4.z + w4.w * g4.w;
    }
    #pragma unroll
    for (int off = 32; off; off >>= 1) acc += __shfl_down(acc, off, 64);
    if (lane == 0) xbuf[i * (2 * GOUT) + rr] = acc + gb[r];   // parity 0
}

// ---------------- K1: per (slice, head): LN + QKV + scores + O + W1 partial ----------------
// R10 body with (a) fused Q/K/V matmul (one pass over rows: 72 vs 96 LDS
// b128 reads/thread, identical per-output summation order) and (b) per-wave
// row-ownership for scores->o->W1 (wave w owns rows 6w..6w+5; both
// inter-phase barriers removed; 5 -> 3 barriers).
__global__ __launch_bounds__(256) void k_attn(
    const float* __restrict__ xm1, const float* __restrict__ xm2,
    const float* __restrict__ lnxg, const float* __restrict__ lnxb,
    const float* __restrict__ lnyg, const float* __restrict__ lnyb,
    const float* __restrict__ wqw, const float* __restrict__ wqb,
    const float* __restrict__ wkw, const float* __restrict__ wkb,
    const float* __restrict__ wvw, const float* __restrict__ wvb,
    const float* __restrict__ l1w,
    float* __restrict__ xpart, int l)
{
    int s = blockIdx.x >> 4, h = blockIdx.x & 15;
    int tid = threadIdx.x;
    int ls = l * S + s;
    int jj = tid & 31;
    int rb = tid >> 5;                 // base row; owns rows rb, rb+8, rb+16
    __shared__ float xn[768], yn[768], vv[768], oo[768];
    __shared__ float q[864], kk[864];          // 24 rows x stride 36 (padded)
    __shared__ float sc[576];
    __shared__ float red[16];
    __shared__ float wqs[1152], wks[1152], wvs[1152], w1s[1152];   // [32][36] padded

    // ---- a-loads issued FIRST (their wait doesn't include the prefetches) ----
    int r1 = (tid + 256) >> 5;
    float av0 = xm1[s * 384 + rb * 32 + jj];                        // rows 0..7
    float av1 = (r1 < S) ? xm1[s * 384 + r1 * 32 + jj]
                         : xm2[(r1 - S) * 384 + s * 32 + jj];       // rows 8..15
    float av2 = xm2[(((tid + 512) >> 5) - S) * 384 + s * 32 + jj];  // rows 16..23

    // ---- prefetch: LN gains/biases, QKV biases, weights ----
    const float* gx = lnxg + ls * 768; const float* bx = lnxb + ls * 768;
    const float* gy = lnyg + ls * 768; const float* by = lnyb + ls * 768;
    float gx0 = gx[tid], gx1 = gx[tid + 256], gx2 = gx[tid + 512];
    float bx0 = bx[tid], bx1 = bx[tid + 256], bx2 = bx[tid + 512];
    float gy0 = gy[tid], gy1 = gy[tid + 256], gy2 = gy[tid + 512];
    float by0 = by[tid], by1 = by[tid + 256], by2 = by[tid + 512];
    float qbv = wqb[ls * 512 + h * 32 + jj];
    float kbv = wkb[ls * 512 + h * 32 + jj];
    float vbv = wvb[ls * 512 + h * 32 + jj];
    int wrow = tid >> 3, wcol = (tid << 2) & 31;   // float4 #tid = (row, col)
    float4 pq = *(const float4*)(wqw + (size_t)ls * 16384 + h * 1024 + tid * 4);
    float4 pk = *(const float4*)(wkw + (size_t)ls * 16384 + h * 1024 + tid * 4);
    float4 pv = *(const float4*)(wvw + (size_t)ls * 16384 + h * 1024 + tid * 4);
    float4 p1 = *(const float4*)(l1w + (size_t)ls * 16384 + h * 32 + wrow * 512 + wcol);

    // ---- LN stats from registers ----
    {
        float s1 = av0 + av1 + av2;
        float s2 = av0 * av0 + av1 * av1 + av2 * av2;
        #pragma unroll
        for (int off = 32; off; off >>= 1) { s1 += __shfl_down(s1, off, 64); s2 += __shfl_down(s2, off, 64); }
        if ((tid & 63) == 0) { red[(tid >> 6) * 2] = s1; red[(tid >> 6) * 2 + 1] = s2; }
    }
    __syncthreads();

    float mu, rs;
    {
        float t1 = red[0] + red[2] + red[4] + red[6];
        float t2 = red[1] + red[3] + red[5] + red[7];
        mu = t1 * (1.f / 768.f);
        float var = t2 * (1.f / 768.f) - mu * mu;
        rs = rsqrtf(var + EPS);
    }

    // ---- LN apply from registers + stage weights to LDS ----
    {
        float zn = (av0 - mu) * rs;
        xn[tid] = zn * gx0 + bx0;           yn[tid] = zn * gy0 + by0;
        zn = (av1 - mu) * rs;
        xn[tid + 256] = zn * gx1 + bx1;     yn[tid + 256] = zn * gy1 + by1;
        zn = (av2 - mu) * rs;
        xn[tid + 512] = zn * gx2 + bx2;     yn[tid + 512] = zn * gy2 + by2;
    }
    *(float4*)(wqs + wrow * 36 + wcol) = pq;
    *(float4*)(wks + wrow * 36 + wcol) = pk;
    *(float4*)(wvs + wrow * 36 + wcol) = pv;
    *(float4*)(w1s + wrow * 36 + wcol) = p1;
    __syncthreads();

    // ---- fused QKV: one pass over rows; 9 accumulators ----
    {
        float aq[3], ak[3], av[3];
        #pragma unroll
        for (int ri = 0; ri < 3; ri++) { aq[ri] = qbv; ak[ri] = kbv; av[ri] = vbv; }
        #pragma unroll
        for (int c4 = 0; c4 < 8; c4++) {
            float4 wq4 = *(const float4*)(wqs + jj * 36 + c4 * 4);
            float4 wk4 = *(const float4*)(wks + jj * 36 + c4 * 4);
            float4 wv4 = *(const float4*)(wvs + jj * 36 + c4 * 4);
            #pragma unroll
            for (int ri = 0; ri < 3; ri++) {
                int r = rb + ri * 8;
                float4 xv = *(const float4*)(xn + r * 32 + c4 * 4);
                float4 yv = *(const float4*)(yn + r * 32 + c4 * 4);
                aq[ri] += dot4(xv, wq4);
                ak[ri] += dot4(yv, wk4);
                av[ri] += dot4(yv, wv4);
            }
        }
        #pragma unroll
        for (int ri = 0; ri < 3; ri++) {
            int r = rb + ri * 8;
            q[r * 36 + jj] = aq[ri];
            kk[r * 36 + jj] = ak[ri];
            vv[r * 32 + jj] = av[ri];
        }
    }
    __syncthreads();

    // ---- per-wave fused scores -> o -> W1 (wave w owns rows 6w..6w+5) ----
    int wv = tid >> 6;
    int lane = tid & 63;
    float* xp = xpart + (s * 16 + h) * 768;

    // scores 6x24 for own rows
    for (int idx = lane; idx < 144; idx += 64) {
        int rl = idx / 24, j = idx - rl * 24;
        int r = wv * 6 + rl;
        const float4* qr = (const float4*)(q + r * 36);
        const float4* kr = (const float4*)(kk + j * 36);
        float acc = 0.f;
        #pragma unroll
        for (int c4 = 0; c4 < 8; c4++) acc += dot4(qr[c4], kr[c4]);
        sc[r * 24 + j] = acc * 0.17677669529663687f;   // 1/sqrt(32)
    }
    // o = sc @ v for own rows (same-wave LDS RAW: hardware in-order + lgkmcnt)
    for (int idx = lane; idx < 192; idx += 64) {
        int rl = idx >> 5, c = idx & 31;
        int r = wv * 6 + rl;
        const float* sr = sc + r * 24;
        float acc = 0.f;
        #pragma unroll
        for (int j = 0; j < 24; j++) acc += sr[j] * vv[j * 32 + c];
        oo[r * 32 + c] = acc;
    }
    // xpart = o @ w1^T for own rows
    for (int idx = lane; idx < 192; idx += 64) {
        int rl = idx >> 5, j = idx & 31;
        int r = wv * 6 + rl;
        const float4* orow = (const float4*)(oo + r * 32);
        float acc = 0.f;
        #pragma unroll
        for (int c4 = 0; c4 < 8; c4++) acc += dot4(orow[c4], *(const float4*)(w1s + j * 36 + c4 * 4));
        xp[r * 32 + j] = acc;
    }
}

// ---------------- K2: r-split FFN, 144 blocks x 256 threads, weights prefetched ----------------
__global__ __launch_bounds__(256) void k_ffn(
    const float* __restrict__ xm1, const float* __restrict__ xm2,
    const float* __restrict__ xpart,
    const float* __restrict__ l1b,
    const float* __restrict__ lnfg, const float* __restrict__ lnfb,
    const float* __restrict__ l2w, const float* __restrict__ l2b,
    const float* __restrict__ l3w, const float* __restrict__ l3b,
    float* __restrict__ out_m1, float* __restrict__ out_m2,
    float* __restrict__ outp, int i1, int i2, int l)
{
    int s = blockIdx.x / 12, rg = blockIdx.x % 12;
    int r0 = rg * 2;
    int tid = threadIdx.x;
    int ls = l * S + s;
    int jj = tid & 31;
    __shared__ float x[768], hn2[64], g2[256];
    __shared__ float red[16];
    __shared__ float w2s[4608];    // [128][36] padded
    __shared__ float w3s[4224];    // [32][132] padded

    // ---- prefetch weights + biases + LN params ----
    float4 pw2[4], pw3[4];
    const float4* w2g = (const float4*)(l2w + (size_t)ls * 4096);
    const float4* w3g = (const float4*)(l3w + (size_t)ls * 4096);
    #pragma unroll
    for (int k = 0; k < 4; k++) { pw2[k] = w2g[tid + k * 256]; pw3[k] = w3g[tid + k * 256]; }
    float b1v = l1b[ls * 32 + jj];
    float b2v = l2b[ls * 128 + (tid & 127)];
    float b3v = l3b[ls * 32 + ((tid >> 2) & 31)];
    int idxl = (r0 + (tid >> 5)) * 32 + jj;      // valid for tid < 64
    float lg = 0.f, lb = 0.f;
    if (tid < 64) { lg = lnfg[ls * 768 + idxl]; lb = lnfb[ls * 768 + idxl]; }

    // ---- x = a + b1 + sum of 16 head partials, LN stats fused ----
    {
        float s1 = 0.f, s2 = 0.f;
        for (int idx = tid; idx < 768; idx += 256) {
            int r = idx >> 5;
            float av = (r < S) ? xm1[s * 384 + r * 32 + jj]
                               : xm2[(r - S) * 384 + s * 32 + jj];
            float acc = av + b1v;
            const float* xp = xpart + s * 16 * 768 + idx;
            #pragma unroll
            for (int hh = 0; hh < 16; hh++) acc += xp[hh * 768];
            x[idx] = acc;
            s1 += acc; s2 += acc * acc;
        }
        #pragma unroll
        for (int off = 32; off; off >>= 1) { s1 += __shfl_down(s1, off, 64); s2 += __shfl_down(s2, off, 64); }
        if ((tid & 63) == 0) { red[(tid >> 6) * 2] = s1; red[(tid >> 6) * 2 + 1] = s2; }
    }
    __syncthreads();

    float mu, rs;
    {
        float t1 = red[0] + red[2] + red[4] + red[6];
        float t2 = red[1] + red[3] + red[5] + red[7];
        mu = t1 * (1.f / 768.f);
        float var = t2 * (1.f / 768.f) - mu * mu;
        rs = rsqrtf(var + EPS);
    }

    // ---- LN apply for own 2 rows (prefetched gains) ----
    if (tid < 64) hn2[tid] = (x[idxl] - mu) * rs * lg + lb;

    // ---- stage W2/W3 to LDS (padded rows) ----
    #pragma unroll
    for (int k = 0; k < 4; k++) {
        int e = tid + k * 256;
        *(float4*)(w2s + (e >> 3) * 36 + ((e << 2) & 31)) = pw2[k];
        *(float4*)(w3s + (e >> 5) * 132 + ((e << 2) & 127)) = pw3[k];
    }
    __syncthreads();

    // ---- g2 = gelu(hn2 @ W2^T + b2): 2 rows x 128 dots, 1/thread ----
    {
        int rr = tid >> 7, u = tid & 127;
        const float4* hr = (const float4*)(hn2 + rr * 32);
        float acc = b2v;
        #pragma unroll
        for (int c4 = 0; c4 < 8; c4++) acc += dot4(hr[c4], *(const float4*)(w2s + u * 36 + c4 * 4));
        g2[rr * 128 + u] = acc * 0.5f * (1.f + erff(acc * 0.70710678118654752f));
    }
    __syncthreads();

    // ---- out = x + g2 @ W3^T + b3 for own 2 rows (4-way u-split per output) ----
    {
        int oi = tid >> 2, qq = tid & 3;     // 64 outputs x 4 lanes
        int rr = oi >> 5, j = oi & 31;
        int r = r0 + rr;
        const float4* gr = (const float4*)(g2 + rr * 128);
        float p = 0.f;
        #pragma unroll
        for (int u4 = qq * 8; u4 < qq * 8 + 8; u4++) p += dot4(gr[u4], *(const float4*)(w3s + j * 132 + u4 * 4));
        p += __shfl_down(p, 2, 4);
        p += __shfl_down(p, 1, 4);
        if (qq == 0) {
            float val = x[r * 32 + j] + b3v + p;
            if (r < S) {
                out_m1[s * 384 + r * 32 + j] = val;
                if (i1 >= 0) outp[((s * 3 + i1) * 12 + r) * 32 + j] = val;
            } else {
                out_m2[s * 384 + (r - S) * 32 + j] = val;
                if (i2 >= 0) outp[((s * 3 + i2) * 12 + (r - S)) * 32 + j] = val;
            }
        }
    }
}

extern "C" void kernel_launch(void* const* d_in, const int* in_sizes, int n_in,
                              void* d_out, int out_size, void* d_ws, size_t ws_size,
                              hipStream_t stream) {
    const float* input_t = (const float*)d_in[0];
    const float* input_s = (const float*)d_in[1];
    const float* s2g_w   = (const float*)d_in[2];
    const float* s2g_b   = (const float*)d_in[3];
    const float* g2g_w   = (const float*)d_in[4];
    const float* g2g_b   = (const float*)d_in[5];
    const float* lnx_g   = (const float*)d_in[6];
    const float* lnx_b   = (const float*)d_in[7];
    const float* lny_g   = (const float*)d_in[8];
    const float* lny_b   = (const float*)d_in[9];
    const float* lnf_g   = (const float*)d_in[10];
    const float* lnf_b   = (const float*)d_in[11];
    const float* wq_w    = (const float*)d_in[12];
    const float* wq_b    = (const float*)d_in[13];
    const float* wk_w    = (const float*)d_in[14];
    const float* wk_b    = (const float*)d_in[15];
    const float* wv_w    = (const float*)d_in[16];
    const float* wv_b    = (const float*)d_in[17];
    const float* l1_w    = (const float*)d_in[18];
    const float* l1_b    = (const float*)d_in[19];
    const float* l2_w    = (const float*)d_in[20];
    const float* l2_b    = (const float*)d_in[21];
    const float* l3_w    = (const float*)d_in[22];
    const float* l3_b    = (const float*)d_in[23];

    float* ws = (float*)d_ws;
    float* gi    = ws;                       // 3*12240 = 36720
    float* xbuf  = ws + 36720;               // 3*2*4608 = 27648
    float* xpart = ws + 36720 + 27648;       // 12*16*768 = 147456
    float* outp  = (float*)d_out;

    k_prep<<<144, 256, 0, stream>>>(input_t, input_s, s2g_w, s2g_b, gi);
    k_g2g<<<3456, 256, 0, stream>>>(g2g_w, g2g_b, gi, xbuf);

    int par[3] = {0, 0, 0};
    const int pairs[3][2] = {{0, 1}, {2, 0}, {1, 2}};
    for (int l = 0; l < 8; l++) {
        for (int pp = 0; pp < 3; pp++) {
            int m1 = pairs[pp][0], m2 = pairs[pp][1];
            float* in1  = xbuf + m1 * 9216 + par[m1] * 4608;
            float* in2  = xbuf + m2 * 9216 + par[m2] * 4608;
            float* out1 = xbuf + m1 * 9216 + (1 - par[m1]) * 4608;
            float* out2 = xbuf + m2 * 9216 + (1 - par[m2]) * 4608;
            int i1 = -1, i2 = -1;
            if (l == 7 && pp == 1) i2 = 0;
            if (l == 7 && pp == 2) { i1 = 1; i2 = 2; }
            k_attn<<<192, 256, 0, stream>>>(in1, in2,
                lnx_g, lnx_b, lny_g, lny_b,
                wq_w, wq_b, wk_w, wk_b, wv_w, wv_b,
                l1_w, xpart, l);
            k_ffn<<<144, 256, 0, stream>>>(in1, in2, xpart, l1_b,
                lnf_g, lnf_b, l2_w, l2_b, l3_w, l3_b,
                out1, out2, outp, i1, i2, l);
            par[m1] ^= 1; par[m2] ^= 1;
        }
    }
}

// Round 14
// 434.964 us; speedup vs baseline: 3.0816x; 1.1836x over previous
//
#include <hip/hip_runtime.h>
#include <hip/hip_bf16.h>
#include <math.h>

// Sizes
#define S 12
#define C 32
#define T 7
#define GIN 12240         // S*S*(T*S+1)
#define GOUT 4608         // S*S*C
#define EPS 1e-5f

typedef float nfloat4 __attribute__((ext_vector_type(4)));   // native vec for nontemporal builtins

__device__ __forceinline__ float dot4(float4 a, float4 b) {
    return a.x * b.x + a.y * b.y + a.z * b.z + a.w * b.w;
}

// ---------------- prep: build gi[3][12240] ----------------
__global__ __launch_bounds__(256) void k_prep(
    const float* __restrict__ it, const float* __restrict__ is_,
    const float* __restrict__ s2w, const float* __restrict__ s2b,
    float* __restrict__ gi)
{
    int idx = blockIdx.x * 256 + threadIdx.x;
    if (idx >= 3 * GIN) return;
    int i = idx / GIN, rem = idx % GIN;
    int ab = rem / 85, e = rem % 85;
    int a = ab / S, b = ab % S;
    float val;
    if (e < 84) {
        int k = e / T, t = e % T;
        int x, y, z;
        if (i == 0)      { x = a; y = b; z = k; }
        else if (i == 1) { x = b; y = k; z = a; }
        else             { x = k; y = a; z = b; }
        val = it[((t * S + x) * S + y) * S + z];
    } else {
        float acc = s2b[i * 144 + ab];
        const float* wr = s2w + (i * 144 + ab) * 8;
        #pragma unroll
        for (int u = 0; u < 8; u++) acc += wr[u] * is_[u];
        val = acc;
    }
    gi[idx] = val;
}

// ---------------- g2g: x[i] = W[i] @ gi[i] + b[i], one wave per row ----------------
// Dual accumulators (halve dependent-FMA chain) + nontemporal W stream.
__global__ __launch_bounds__(256) void k_g2g(
    const float* __restrict__ W, const float* __restrict__ gb,
    const float* __restrict__ gi, float* __restrict__ xbuf)
{
    int wave = threadIdx.x >> 6;
    int lane = threadIdx.x & 63;
    int r = blockIdx.x * 4 + wave;          // 0..13823
    int i = r / GOUT, rr = r % GOUT;
    const nfloat4* Wr = reinterpret_cast<const nfloat4*>(W + (size_t)r * GIN);
    const float4* gv = reinterpret_cast<const float4*>(gi + i * GIN);
    float acc0 = 0.f, acc1 = 0.f;
    int k = lane;
    for (; k + 64 < GIN / 4; k += 128) {
        nfloat4 w0 = __builtin_nontemporal_load(&Wr[k]);
        float4 g0 = gv[k];
        acc0 += w0.x * g0.x + w0.y * g0.y + w0.z * g0.z + w0.w * g0.w;
        nfloat4 w1 = __builtin_nontemporal_load(&Wr[k + 64]);
        float4 g1 = gv[k + 64];
        acc1 += w1.x * g1.x + w1.y * g1.y + w1.z * g1.z + w1.w * g1.w;
    }
    if (k < GIN / 4) {
        nfloat4 w0 = __builtin_nontemporal_load(&Wr[k]);
        float4 g0 = gv[k];
        acc0 += w0.x * g0.x + w0.y * g0.y + w0.z * g0.z + w0.w * g0.w;
    }
    float acc = acc0 + acc1;
    #pragma unroll
    for (int off = 32; off; off >>= 1) acc += __shfl_down(acc, off, 64);
    if (lane == 0) xbuf[i * (2 * GOUT) + rr] = acc + gb[r];   // parity 0
}

// ---------------- K1: per (slice, head): LN + QKV + scores + O + W1 partial ----------------
__global__ __launch_bounds__(256) void k_attn(
    const float* __restrict__ xm1, const float* __restrict__ xm2,
    const float* __restrict__ lnxg, const float* __restrict__ lnxb,
    const float* __restrict__ lnyg, const float* __restrict__ lnyb,
    const float* __restrict__ wqw, const float* __restrict__ wqb,
    const float* __restrict__ wkw, const float* __restrict__ wkb,
    const float* __restrict__ wvw, const float* __restrict__ wvb,
    const float* __restrict__ l1w,
    float* __restrict__ xpart, int l)
{
    int s = blockIdx.x >> 4, h = blockIdx.x & 15;
    int tid = threadIdx.x;
    int ls = l * S + s;
    int jj = tid & 31;
    int rb = tid >> 5;                 // base row; owns rows rb, rb+8, rb+16
    __shared__ float xn[768], yn[768], vv[768], oo[768];
    __shared__ float q[864], kk[864];          // 24 rows x stride 36 (padded)
    __shared__ float sc[576];
    __shared__ float red[16];
    __shared__ float wqs[1152], wks[1152], wvs[1152], w1s[1152];   // [32][36] padded

    // ---- a-loads issued FIRST (their wait doesn't include the prefetches) ----
    int r1 = (tid + 256) >> 5;
    float av0 = xm1[s * 384 + rb * 32 + jj];                        // rows 0..7
    float av1 = (r1 < S) ? xm1[s * 384 + r1 * 32 + jj]
                         : xm2[(r1 - S) * 384 + s * 32 + jj];       // rows 8..15
    float av2 = xm2[(((tid + 512) >> 5) - S) * 384 + s * 32 + jj];  // rows 16..23

    // ---- prefetch: LN gains/biases, QKV biases, weights ----
    const float* gx = lnxg + ls * 768; const float* bx = lnxb + ls * 768;
    const float* gy = lnyg + ls * 768; const float* by = lnyb + ls * 768;
    float gx0 = gx[tid], gx1 = gx[tid + 256], gx2 = gx[tid + 512];
    float bx0 = bx[tid], bx1 = bx[tid + 256], bx2 = bx[tid + 512];
    float gy0 = gy[tid], gy1 = gy[tid + 256], gy2 = gy[tid + 512];
    float by0 = by[tid], by1 = by[tid + 256], by2 = by[tid + 512];
    float qbv = wqb[ls * 512 + h * 32 + jj];
    float kbv = wkb[ls * 512 + h * 32 + jj];
    float vbv = wvb[ls * 512 + h * 32 + jj];
    int wrow = tid >> 3, wcol = (tid << 2) & 31;   // float4 #tid = (row, col)
    float4 pq = *(const float4*)(wqw + (size_t)ls * 16384 + h * 1024 + tid * 4);
    float4 pk = *(const float4*)(wkw + (size_t)ls * 16384 + h * 1024 + tid * 4);
    float4 pv = *(const float4*)(wvw + (size_t)ls * 16384 + h * 1024 + tid * 4);
    float4 p1 = *(const float4*)(l1w + (size_t)ls * 16384 + h * 32 + wrow * 512 + wcol);

    // ---- LN stats from registers ----
    {
        float s1 = av0 + av1 + av2;
        float s2 = av0 * av0 + av1 * av1 + av2 * av2;
        #pragma unroll
        for (int off = 32; off; off >>= 1) { s1 += __shfl_down(s1, off, 64); s2 += __shfl_down(s2, off, 64); }
        if ((tid & 63) == 0) { red[(tid >> 6) * 2] = s1; red[(tid >> 6) * 2 + 1] = s2; }
    }
    __syncthreads();

    float mu, rs;
    {
        float t1 = red[0] + red[2] + red[4] + red[6];
        float t2 = red[1] + red[3] + red[5] + red[7];
        mu = t1 * (1.f / 768.f);
        float var = t2 * (1.f / 768.f) - mu * mu;
        rs = rsqrtf(var + EPS);
    }

    // ---- LN apply from registers + stage weights to LDS ----
    {
        float zn = (av0 - mu) * rs;
        xn[tid] = zn * gx0 + bx0;           yn[tid] = zn * gy0 + by0;
        zn = (av1 - mu) * rs;
        xn[tid + 256] = zn * gx1 + bx1;     yn[tid + 256] = zn * gy1 + by1;
        zn = (av2 - mu) * rs;
        xn[tid + 512] = zn * gx2 + bx2;     yn[tid + 512] = zn * gy2 + by2;
    }
    *(float4*)(wqs + wrow * 36 + wcol) = pq;
    *(float4*)(wks + wrow * 36 + wcol) = pk;
    *(float4*)(wvs + wrow * 36 + wcol) = pv;
    *(float4*)(w1s + wrow * 36 + wcol) = p1;
    __syncthreads();

    // ---- fused QKV: one pass over rows; 9 accumulators ----
    {
        float aq[3], ak[3], av[3];
        #pragma unroll
        for (int ri = 0; ri < 3; ri++) { aq[ri] = qbv; ak[ri] = kbv; av[ri] = vbv; }
        #pragma unroll
        for (int c4 = 0; c4 < 8; c4++) {
            float4 wq4 = *(const float4*)(wqs + jj * 36 + c4 * 4);
            float4 wk4 = *(const float4*)(wks + jj * 36 + c4 * 4);
            float4 wv4 = *(const float4*)(wvs + jj * 36 + c4 * 4);
            #pragma unroll
            for (int ri = 0; ri < 3; ri++) {
                int r = rb + ri * 8;
                float4 xv = *(const float4*)(xn + r * 32 + c4 * 4);
                float4 yv = *(const float4*)(yn + r * 32 + c4 * 4);
                aq[ri] += dot4(xv, wq4);
                ak[ri] += dot4(yv, wk4);
                av[ri] += dot4(yv, wv4);
            }
        }
        #pragma unroll
        for (int ri = 0; ri < 3; ri++) {
            int r = rb + ri * 8;
            q[r * 36 + jj] = aq[ri];
            kk[r * 36 + jj] = ak[ri];
            vv[r * 32 + jj] = av[ri];
        }
    }
    __syncthreads();

    // ---- per-wave fused scores -> o -> W1 (wave w owns rows 6w..6w+5) ----
    int wv = tid >> 6;
    int lane = tid & 63;
    float* xp = xpart + (s * 16 + h) * 768;

    // scores 6x24 for own rows
    for (int idx = lane; idx < 144; idx += 64) {
        int rl = idx / 24, j = idx - rl * 24;
        int r = wv * 6 + rl;
        const float4* qr = (const float4*)(q + r * 36);
        const float4* kr = (const float4*)(kk + j * 36);
        float acc = 0.f;
        #pragma unroll
        for (int c4 = 0; c4 < 8; c4++) acc += dot4(qr[c4], kr[c4]);
        sc[r * 24 + j] = acc * 0.17677669529663687f;   // 1/sqrt(32)
    }
    // o = sc @ v for own rows, float4 over columns (lanes 0..47; same
    // per-output summation order as scalar version)
    if (lane < 48) {
        int rl = lane >> 3, c4 = lane & 7;
        int r = wv * 6 + rl;
        const float* sr = sc + r * 24;
        float4 acc = make_float4(0.f, 0.f, 0.f, 0.f);
        #pragma unroll
        for (int j = 0; j < 24; j++) {
            float sv = sr[j];
            float4 vj = *(const float4*)(vv + j * 32 + c4 * 4);
            acc.x += sv * vj.x; acc.y += sv * vj.y;
            acc.z += sv * vj.z; acc.w += sv * vj.w;
        }
        *(float4*)(oo + r * 32 + c4 * 4) = acc;
    }
    // xpart = o @ w1^T for own rows (same-wave LDS RAW: in-order + lgkmcnt)
    for (int idx = lane; idx < 192; idx += 64) {
        int rl = idx >> 5, j = idx & 31;
        int r = wv * 6 + rl;
        const float4* orow = (const float4*)(oo + r * 32);
        float acc = 0.f;
        #pragma unroll
        for (int c4 = 0; c4 < 8; c4++) acc += dot4(orow[c4], *(const float4*)(w1s + j * 36 + c4 * 4));
        xp[r * 32 + j] = acc;
    }
}

// ---------------- K2: r-split FFN, 144 blocks x 256 threads ----------------
// x-build vectorized to float4 (threads 0..191 own one 4-col chunk).
__global__ __launch_bounds__(256) void k_ffn(
    const float* __restrict__ xm1, const float* __restrict__ xm2,
    const float* __restrict__ xpart,
    const float* __restrict__ l1b,
    const float* __restrict__ lnfg, const float* __restrict__ lnfb,
    const float* __restrict__ l2w, const float* __restrict__ l2b,
    const float* __restrict__ l3w, const float* __restrict__ l3b,
    float* __restrict__ out_m1, float* __restrict__ out_m2,
    float* __restrict__ outp, int i1, int i2, int l)
{
    int s = blockIdx.x / 12, rg = blockIdx.x % 12;
    int r0 = rg * 2;
    int tid = threadIdx.x;
    int ls = l * S + s;
    int jj = tid & 31;
    __shared__ float x[768], hn2[64], g2[256];
    __shared__ float red[16];
    __shared__ float w2s[4608];    // [128][36] padded
    __shared__ float w3s[4224];    // [32][132] padded

    // ---- prefetch weights + biases + LN params ----
    float4 pw2[4], pw3[4];
    const float4* w2g = (const float4*)(l2w + (size_t)ls * 4096);
    const float4* w3g = (const float4*)(l3w + (size_t)ls * 4096);
    #pragma unroll
    for (int k = 0; k < 4; k++) { pw2[k] = w2g[tid + k * 256]; pw3[k] = w3g[tid + k * 256]; }
    int xr = tid >> 3, xc4 = tid & 7;            // chunk (row, 4-col group), tid<192
    float4 b1v4 = *(const float4*)(l1b + ls * 32 + xc4 * 4);
    float b2v = l2b[ls * 128 + (tid & 127)];
    float b3v = l3b[ls * 32 + ((tid >> 2) & 31)];
    int idxl = (r0 + (tid >> 5)) * 32 + jj;      // valid for tid < 64
    float lg = 0.f, lb = 0.f;
    if (tid < 64) { lg = lnfg[ls * 768 + idxl]; lb = lnfb[ls * 768 + idxl]; }

    // ---- x = a + b1 + sum of 16 head partials (float4), LN stats fused ----
    {
        float s1 = 0.f, s2 = 0.f;
        if (tid < 192) {
            float4 acc = (xr < S) ? *(const float4*)(xm1 + s * 384 + xr * 32 + xc4 * 4)
                                  : *(const float4*)(xm2 + (xr - S) * 384 + s * 32 + xc4 * 4);
            acc.x += b1v4.x; acc.y += b1v4.y; acc.z += b1v4.z; acc.w += b1v4.w;
            const float* xp = xpart + s * 16 * 768 + tid * 4;
            #pragma unroll
            for (int hh = 0; hh < 16; hh++) {
                float4 p = *(const float4*)(xp + hh * 768);
                acc.x += p.x; acc.y += p.y; acc.z += p.z; acc.w += p.w;
            }
            *(float4*)(x + tid * 4) = acc;
            s1 = acc.x + acc.y + acc.z + acc.w;
            s2 = acc.x * acc.x + acc.y * acc.y + acc.z * acc.z + acc.w * acc.w;
        }
        #pragma unroll
        for (int off = 32; off; off >>= 1) { s1 += __shfl_down(s1, off, 64); s2 += __shfl_down(s2, off, 64); }
        if ((tid & 63) == 0) { red[(tid >> 6) * 2] = s1; red[(tid >> 6) * 2 + 1] = s2; }
    }
    __syncthreads();

    float mu, rs;
    {
        float t1 = red[0] + red[2] + red[4] + red[6];
        float t2 = red[1] + red[3] + red[5] + red[7];
        mu = t1 * (1.f / 768.f);
        float var = t2 * (1.f / 768.f) - mu * mu;
        rs = rsqrtf(var + EPS);
    }

    // ---- LN apply for own 2 rows (prefetched gains) ----
    if (tid < 64) hn2[tid] = (x[idxl] - mu) * rs * lg + lb;

    // ---- stage W2/W3 to LDS (padded rows) ----
    #pragma unroll
    for (int k = 0; k < 4; k++) {
        int e = tid + k * 256;
        *(float4*)(w2s + (e >> 3) * 36 + ((e << 2) & 31)) = pw2[k];
        *(float4*)(w3s + (e >> 5) * 132 + ((e << 2) & 127)) = pw3[k];
    }
    __syncthreads();

    // ---- g2 = gelu(hn2 @ W2^T + b2): 2 rows x 128 dots, 1/thread ----
    {
        int rr = tid >> 7, u = tid & 127;
        const float4* hr = (const float4*)(hn2 + rr * 32);
        float acc = b2v;
        #pragma unroll
        for (int c4 = 0; c4 < 8; c4++) acc += dot4(hr[c4], *(const float4*)(w2s + u * 36 + c4 * 4));
        g2[rr * 128 + u] = acc * 0.5f * (1.f + erff(acc * 0.70710678118654752f));
    }
    __syncthreads();

    // ---- out = x + g2 @ W3^T + b3 for own 2 rows (4-way u-split per output) ----
    {
        int oi = tid >> 2, qq = tid & 3;     // 64 outputs x 4 lanes
        int rr = oi >> 5, j = oi & 31;
        int r = r0 + rr;
        const float4* gr = (const float4*)(g2 + rr * 128);
        float p = 0.f;
        #pragma unroll
        for (int u4 = qq * 8; u4 < qq * 8 + 8; u4++) p += dot4(gr[u4], *(const float4*)(w3s + j * 132 + u4 * 4));
        p += __shfl_down(p, 2, 4);
        p += __shfl_down(p, 1, 4);
        if (qq == 0) {
            float val = x[r * 32 + j] + b3v + p;
            if (r < S) {
                out_m1[s * 384 + r * 32 + j] = val;
                if (i1 >= 0) outp[((s * 3 + i1) * 12 + r) * 32 + j] = val;
            } else {
                out_m2[s * 384 + (r - S) * 32 + j] = val;
                if (i2 >= 0) outp[((s * 3 + i2) * 12 + (r - S)) * 32 + j] = val;
            }
        }
    }
}

extern "C" void kernel_launch(void* const* d_in, const int* in_sizes, int n_in,
                              void* d_out, int out_size, void* d_ws, size_t ws_size,
                              hipStream_t stream) {
    const float* input_t = (const float*)d_in[0];
    const float* input_s = (const float*)d_in[1];
    const float* s2g_w   = (const float*)d_in[2];
    const float* s2g_b   = (const float*)d_in[3];
    const float* g2g_w   = (const float*)d_in[4];
    const float* g2g_b   = (const float*)d_in[5];
    const float* lnx_g   = (const float*)d_in[6];
    const float* lnx_b   = (const float*)d_in[7];
    const float* lny_g   = (const float*)d_in[8];
    const float* lny_b   = (const float*)d_in[9];
    const float* lnf_g   = (const float*)d_in[10];
    const float* lnf_b   = (const float*)d_in[11];
    const float* wq_w    = (const float*)d_in[12];
    const float* wq_b    = (const float*)d_in[13];
    const float* wk_w    = (const float*)d_in[14];
    const float* wk_b    = (const float*)d_in[15];
    const float* wv_w    = (const float*)d_in[16];
    const float* wv_b    = (const float*)d_in[17];
    const float* l1_w    = (const float*)d_in[18];
    const float* l1_b    = (const float*)d_in[19];
    const float* l2_w    = (const float*)d_in[20];
    const float* l2_b    = (const float*)d_in[21];
    const float* l3_w    = (const float*)d_in[22];
    const float* l3_b    = (const float*)d_in[23];

    float* ws = (float*)d_ws;
    float* gi    = ws;                       // 3*12240 = 36720
    float* xbuf  = ws + 36720;               // 3*2*4608 = 27648
    float* xpart = ws + 36720 + 27648;       // 12*16*768 = 147456
    float* outp  = (float*)d_out;

    k_prep<<<144, 256, 0, stream>>>(input_t, input_s, s2g_w, s2g_b, gi);
    k_g2g<<<3456, 256, 0, stream>>>(g2g_w, g2g_b, gi, xbuf);

    int par[3] = {0, 0, 0};
    const int pairs[3][2] = {{0, 1}, {2, 0}, {1, 2}};
    for (int l = 0; l < 8; l++) {
        for (int pp = 0; pp < 3; pp++) {
            int m1 = pairs[pp][0], m2 = pairs[pp][1];
            float* in1  = xbuf + m1 * 9216 + par[m1] * 4608;
            float* in2  = xbuf + m2 * 9216 + par[m2] * 4608;
            float* out1 = xbuf + m1 * 9216 + (1 - par[m1]) * 4608;
            float* out2 = xbuf + m2 * 9216 + (1 - par[m2]) * 4608;
            int i1 = -1, i2 = -1;
            if (l == 7 && pp == 1) i2 = 0;
            if (l == 7 && pp == 2) { i1 = 1; i2 = 2; }
            k_attn<<<192, 256, 0, stream>>>(in1, in2,
                lnx_g, lnx_b, lny_g, lny_b,
                wq_w, wq_b, wk_w, wk_b, wv_w, wv_b,
                l1_w, xpart, l);
            k_ffn<<<144, 256, 0, stream>>>(in1, in2, xpart, l1_b,
                lnf_g, lnf_b, l2_w, l2_b, l3_w, l3_b,
                out1, out2, outp, i1, i2, l);
            par[m1] ^= 1; par[m2] ^= 1;
        }
    }
}

// Round 15
// 427.843 us; speedup vs baseline: 3.1328x; 1.0166x over previous
//
#include <hip/hip_runtime.h>
#include <hip/hip_bf16.h>
#include <math.h>

// Sizes
#define S 12
#define C 32
#define T 7
#define GIN 12240         // S*S*(T*S+1)
#define GOUT 4608         // S*S*C
#define EPS 1e-5f

typedef float nfloat4 __attribute__((ext_vector_type(4)));   // native vec for nontemporal builtins

__device__ __forceinline__ float dot4(float4 a, float4 b) {
    return a.x * b.x + a.y * b.y + a.z * b.z + a.w * b.w;
}

// ---------------- prep: build gi[3][12240] ----------------
__global__ __launch_bounds__(256) void k_prep(
    const float* __restrict__ it, const float* __restrict__ is_,
    const float* __restrict__ s2w, const float* __restrict__ s2b,
    float* __restrict__ gi)
{
    int idx = blockIdx.x * 256 + threadIdx.x;
    if (idx >= 3 * GIN) return;
    int i = idx / GIN, rem = idx % GIN;
    int ab = rem / 85, e = rem % 85;
    int a = ab / S, b = ab % S;
    float val;
    if (e < 84) {
        int k = e / T, t = e % T;
        int x, y, z;
        if (i == 0)      { x = a; y = b; z = k; }
        else if (i == 1) { x = b; y = k; z = a; }
        else             { x = k; y = a; z = b; }
        val = it[((t * S + x) * S + y) * S + z];
    } else {
        float acc = s2b[i * 144 + ab];
        const float* wr = s2w + (i * 144 + ab) * 8;
        #pragma unroll
        for (int u = 0; u < 8; u++) acc += wr[u] * is_[u];
        val = acc;
    }
    gi[idx] = val;
}

// ---------------- g2g: x[i] = W[i] @ gi[i] + b[i], one wave per row ----------------
__global__ __launch_bounds__(256) void k_g2g(
    const float* __restrict__ W, const float* __restrict__ gb,
    const float* __restrict__ gi, float* __restrict__ xbuf)
{
    int wave = threadIdx.x >> 6;
    int lane = threadIdx.x & 63;
    int r = blockIdx.x * 4 + wave;          // 0..13823
    int i = r / GOUT, rr = r % GOUT;
    const nfloat4* Wr = reinterpret_cast<const nfloat4*>(W + (size_t)r * GIN);
    const float4* gv = reinterpret_cast<const float4*>(gi + i * GIN);
    float acc0 = 0.f, acc1 = 0.f;
    int k = lane;
    for (; k + 64 < GIN / 4; k += 128) {
        nfloat4 w0 = __builtin_nontemporal_load(&Wr[k]);
        float4 g0 = gv[k];
        acc0 += w0.x * g0.x + w0.y * g0.y + w0.z * g0.z + w0.w * g0.w;
        nfloat4 w1 = __builtin_nontemporal_load(&Wr[k + 64]);
        float4 g1 = gv[k + 64];
        acc1 += w1.x * g1.x + w1.y * g1.y + w1.z * g1.z + w1.w * g1.w;
    }
    if (k < GIN / 4) {
        nfloat4 w0 = __builtin_nontemporal_load(&Wr[k]);
        float4 g0 = gv[k];
        acc0 += w0.x * g0.x + w0.y * g0.y + w0.z * g0.z + w0.w * g0.w;
    }
    float acc = acc0 + acc1;
    #pragma unroll
    for (int off = 32; off; off >>= 1) acc += __shfl_down(acc, off, 64);
    if (lane == 0) xbuf[i * (2 * GOUT) + rr] = acc + gb[r];   // parity 0
}

// ---------------- K1: per (slice, head), 512 threads (2 waves/SIMD) ----------------
// Same algorithm as R14; elems mapped 1.5/thread (pass A = all, pass B = tid<256).
// Barriers: red | xn/yn+weights | qkv | scores. o->W1 stays wave-local.
__global__ __launch_bounds__(512) void k_attn(
    const float* __restrict__ xm1, const float* __restrict__ xm2,
    const float* __restrict__ lnxg, const float* __restrict__ lnxb,
    const float* __restrict__ lnyg, const float* __restrict__ lnyb,
    const float* __restrict__ wqw, const float* __restrict__ wqb,
    const float* __restrict__ wkw, const float* __restrict__ wkb,
    const float* __restrict__ wvw, const float* __restrict__ wvb,
    const float* __restrict__ l1w,
    float* __restrict__ xpart, int l)
{
    int s = blockIdx.x >> 4, h = blockIdx.x & 15;
    int tid = threadIdx.x;
    int ls = l * S + s;
    int jj = tid & 31;
    int r0 = tid >> 5;                     // row for pass A (0..15)
    __shared__ float xn[768], yn[768], vv[768], oo[768];
    __shared__ float q[864], kk[864];      // 24 rows x stride 36 (padded)
    __shared__ float sc[576];
    __shared__ float red[16];
    __shared__ float wqs[1152], wks[1152], wvs[1152], w1s[1152];   // [32][36] padded

    // ---- a-loads issued FIRST ----
    float av0 = (r0 < S) ? xm1[s * 384 + r0 * 32 + jj]
                         : xm2[(r0 - S) * 384 + s * 32 + jj];
    float av1 = 0.f;
    if (tid < 256) av1 = xm2[(((tid + 512) >> 5) - S) * 384 + s * 32 + jj];  // rows 16..23

    // ---- prefetch: LN params, biases, weights (weights by tid<256) ----
    const float* gx = lnxg + ls * 768; const float* bx = lnxb + ls * 768;
    const float* gy = lnyg + ls * 768; const float* by = lnyb + ls * 768;
    float gx0 = gx[tid], bx0 = bx[tid], gy0 = gy[tid], by0 = by[tid];
    float gx1 = 0.f, bx1 = 0.f, gy1 = 0.f, by1 = 0.f;
    if (tid < 256) { gx1 = gx[tid + 512]; bx1 = bx[tid + 512]; gy1 = gy[tid + 512]; by1 = by[tid + 512]; }
    float qbv = wqb[ls * 512 + h * 32 + jj];
    float kbv = wkb[ls * 512 + h * 32 + jj];
    float vbv = wvb[ls * 512 + h * 32 + jj];
    float4 pq, pk, pv, p1;
    int wrow = tid >> 3, wcol = (tid << 2) & 31;
    if (tid < 256) {
        pq = *(const float4*)(wqw + (size_t)ls * 16384 + h * 1024 + tid * 4);
        pk = *(const float4*)(wkw + (size_t)ls * 16384 + h * 1024 + tid * 4);
        pv = *(const float4*)(wvw + (size_t)ls * 16384 + h * 1024 + tid * 4);
        p1 = *(const float4*)(l1w + (size_t)ls * 16384 + h * 32 + wrow * 512 + wcol);
    }

    // ---- LN stats from registers (8 waves) ----
    {
        float s1 = av0 + av1;
        float s2 = av0 * av0 + av1 * av1;
        #pragma unroll
        for (int off = 32; off; off >>= 1) { s1 += __shfl_down(s1, off, 64); s2 += __shfl_down(s2, off, 64); }
        if ((tid & 63) == 0) { red[(tid >> 6) * 2] = s1; red[(tid >> 6) * 2 + 1] = s2; }
    }
    __syncthreads();

    float mu, rs;
    {
        float t1 = 0.f, t2 = 0.f;
        #pragma unroll
        for (int w = 0; w < 8; w++) { t1 += red[w * 2]; t2 += red[w * 2 + 1]; }
        mu = t1 * (1.f / 768.f);
        float var = t2 * (1.f / 768.f) - mu * mu;
        rs = rsqrtf(var + EPS);
    }

    // ---- LN apply from registers + stage weights ----
    {
        float zn = (av0 - mu) * rs;
        xn[tid] = zn * gx0 + bx0;
        yn[tid] = zn * gy0 + by0;
    }
    if (tid < 256) {
        float zn = (av1 - mu) * rs;
        xn[tid + 512] = zn * gx1 + bx1;
        yn[tid + 512] = zn * gy1 + by1;
        *(float4*)(wqs + wrow * 36 + wcol) = pq;
        *(float4*)(wks + wrow * 36 + wcol) = pk;
        *(float4*)(wvs + wrow * 36 + wcol) = pv;
        *(float4*)(w1s + wrow * 36 + wcol) = p1;
    }
    __syncthreads();

    // ---- fused QKV: pass A (row r0) + pass B (row r0+16, tid<256) ----
    {
        float aqA = qbv, akA = kbv, avA = vbv;
        float aqB = qbv, akB = kbv, avB = vbv;
        int rB = (tid >> 5) + 16;
        #pragma unroll
        for (int c4 = 0; c4 < 8; c4++) {
            float4 wq4 = *(const float4*)(wqs + jj * 36 + c4 * 4);
            float4 wk4 = *(const float4*)(wks + jj * 36 + c4 * 4);
            float4 wv4 = *(const float4*)(wvs + jj * 36 + c4 * 4);
            float4 xvA = *(const float4*)(xn + r0 * 32 + c4 * 4);
            float4 yvA = *(const float4*)(yn + r0 * 32 + c4 * 4);
            aqA += dot4(xvA, wq4); akA += dot4(yvA, wk4); avA += dot4(yvA, wv4);
            if (tid < 256) {
                float4 xvB = *(const float4*)(xn + rB * 32 + c4 * 4);
                float4 yvB = *(const float4*)(yn + rB * 32 + c4 * 4);
                aqB += dot4(xvB, wq4); akB += dot4(yvB, wk4); avB += dot4(yvB, wv4);
            }
        }
        q[r0 * 36 + jj] = aqA; kk[r0 * 36 + jj] = akA; vv[r0 * 32 + jj] = avA;
        if (tid < 256) { q[rB * 36 + jj] = aqB; kk[rB * 36 + jj] = akB; vv[rB * 32 + jj] = avB; }
    }
    __syncthreads();

    // ---- scores 24x24 ----
    {
        int idx = tid;
        if (idx < 576) {
            int r = idx / 24, j = idx - r * 24;
            const float4* qr = (const float4*)(q + r * 36);
            const float4* kr = (const float4*)(kk + j * 36);
            float acc = 0.f;
            #pragma unroll
            for (int c4 = 0; c4 < 8; c4++) acc += dot4(qr[c4], kr[c4]);
            sc[idx] = acc * 0.17677669529663687f;   // 1/sqrt(32)
        }
        idx = tid + 512;
        if (tid < 64) {
            int r = idx / 24, j = idx - r * 24;
            const float4* qr = (const float4*)(q + r * 36);
            const float4* kr = (const float4*)(kk + j * 36);
            float acc = 0.f;
            #pragma unroll
            for (int c4 = 0; c4 < 8; c4++) acc += dot4(qr[c4], kr[c4]);
            sc[idx] = acc * 0.17677669529663687f;
        }
    }
    __syncthreads();

    // ---- o = sc @ v: pass A row r0, pass B row r0+16 (wave-local for W1) ----
    {
        const float* srA = sc + r0 * 24;
        float accA = 0.f;
        #pragma unroll
        for (int j = 0; j < 24; j++) accA += srA[j] * vv[j * 32 + jj];
        oo[r0 * 32 + jj] = accA;
        if (tid < 256) {
            int rB = (tid >> 5) + 16;
            const float* srB = sc + rB * 24;
            float accB = 0.f;
            #pragma unroll
            for (int j = 0; j < 24; j++) accB += srB[j] * vv[j * 32 + jj];
            oo[rB * 32 + jj] = accB;
        }
    }
    // ---- xpart = o @ w1^T (same-wave RAW on oo; no barrier) ----
    {
        float* xp = xpart + (s * 16 + h) * 768;
        const float4* orowA = (const float4*)(oo + r0 * 32);
        float accA = 0.f;
        #pragma unroll
        for (int c4 = 0; c4 < 8; c4++) accA += dot4(orowA[c4], *(const float4*)(w1s + jj * 36 + c4 * 4));
        xp[r0 * 32 + jj] = accA;
        if (tid < 256) {
            int rB = (tid >> 5) + 16;
            const float4* orowB = (const float4*)(oo + rB * 32);
            float accB = 0.f;
            #pragma unroll
            for (int c4 = 0; c4 < 8; c4++) accB += dot4(orowB[c4], *(const float4*)(w1s + jj * 36 + c4 * 4));
            xp[rB * 32 + jj] = accB;
        }
    }
}

// ---------------- K2: r-split FFN, 144 blocks x 256 threads (unchanged R14) ----------------
__global__ __launch_bounds__(256) void k_ffn(
    const float* __restrict__ xm1, const float* __restrict__ xm2,
    const float* __restrict__ xpart,
    const float* __restrict__ l1b,
    const float* __restrict__ lnfg, const float* __restrict__ lnfb,
    const float* __restrict__ l2w, const float* __restrict__ l2b,
    const float* __restrict__ l3w, const float* __restrict__ l3b,
    float* __restrict__ out_m1, float* __restrict__ out_m2,
    float* __restrict__ outp, int i1, int i2, int l)
{
    int s = blockIdx.x / 12, rg = blockIdx.x % 12;
    int r0 = rg * 2;
    int tid = threadIdx.x;
    int ls = l * S + s;
    int jj = tid & 31;
    __shared__ float x[768], hn2[64], g2[256];
    __shared__ float red[16];
    __shared__ float w2s[4608];    // [128][36] padded
    __shared__ float w3s[4224];    // [32][132] padded

    // ---- prefetch weights + biases + LN params ----
    float4 pw2[4], pw3[4];
    const float4* w2g = (const float4*)(l2w + (size_t)ls * 4096);
    const float4* w3g = (const float4*)(l3w + (size_t)ls * 4096);
    #pragma unroll
    for (int k = 0; k < 4; k++) { pw2[k] = w2g[tid + k * 256]; pw3[k] = w3g[tid + k * 256]; }
    int xr = tid >> 3, xc4 = tid & 7;            // chunk (row, 4-col group), tid<192
    float4 b1v4 = *(const float4*)(l1b + ls * 32 + xc4 * 4);
    float b2v = l2b[ls * 128 + (tid & 127)];
    float b3v = l3b[ls * 32 + ((tid >> 2) & 31)];
    int idxl = (r0 + (tid >> 5)) * 32 + jj;      // valid for tid < 64
    float lg = 0.f, lb = 0.f;
    if (tid < 64) { lg = lnfg[ls * 768 + idxl]; lb = lnfb[ls * 768 + idxl]; }

    // ---- x = a + b1 + sum of 16 head partials (float4), LN stats fused ----
    {
        float s1 = 0.f, s2 = 0.f;
        if (tid < 192) {
            float4 acc = (xr < S) ? *(const float4*)(xm1 + s * 384 + xr * 32 + xc4 * 4)
                                  : *(const float4*)(xm2 + (xr - S) * 384 + s * 32 + xc4 * 4);
            acc.x += b1v4.x; acc.y += b1v4.y; acc.z += b1v4.z; acc.w += b1v4.w;
            const float* xp = xpart + s * 16 * 768 + tid * 4;
            #pragma unroll
            for (int hh = 0; hh < 16; hh++) {
                float4 p = *(const float4*)(xp + hh * 768);
                acc.x += p.x; acc.y += p.y; acc.z += p.z; acc.w += p.w;
            }
            *(float4*)(x + tid * 4) = acc;
            s1 = acc.x + acc.y + acc.z + acc.w;
            s2 = acc.x * acc.x + acc.y * acc.y + acc.z * acc.z + acc.w * acc.w;
        }
        #pragma unroll
        for (int off = 32; off; off >>= 1) { s1 += __shfl_down(s1, off, 64); s2 += __shfl_down(s2, off, 64); }
        if ((tid & 63) == 0) { red[(tid >> 6) * 2] = s1; red[(tid >> 6) * 2 + 1] = s2; }
    }
    __syncthreads();

    float mu, rs;
    {
        float t1 = red[0] + red[2] + red[4] + red[6];
        float t2 = red[1] + red[3] + red[5] + red[7];
        mu = t1 * (1.f / 768.f);
        float var = t2 * (1.f / 768.f) - mu * mu;
        rs = rsqrtf(var + EPS);
    }

    // ---- LN apply for own 2 rows (prefetched gains) ----
    if (tid < 64) hn2[tid] = (x[idxl] - mu) * rs * lg + lb;

    // ---- stage W2/W3 to LDS (padded rows) ----
    #pragma unroll
    for (int k = 0; k < 4; k++) {
        int e = tid + k * 256;
        *(float4*)(w2s + (e >> 3) * 36 + ((e << 2) & 31)) = pw2[k];
        *(float4*)(w3s + (e >> 5) * 132 + ((e << 2) & 127)) = pw3[k];
    }
    __syncthreads();

    // ---- g2 = gelu(hn2 @ W2^T + b2): 2 rows x 128 dots, 1/thread ----
    {
        int rr = tid >> 7, u = tid & 127;
        const float4* hr = (const float4*)(hn2 + rr * 32);
        float acc = b2v;
        #pragma unroll
        for (int c4 = 0; c4 < 8; c4++) acc += dot4(hr[c4], *(const float4*)(w2s + u * 36 + c4 * 4));
        g2[rr * 128 + u] = acc * 0.5f * (1.f + erff(acc * 0.70710678118654752f));
    }
    __syncthreads();

    // ---- out = x + g2 @ W3^T + b3 for own 2 rows (4-way u-split per output) ----
    {
        int oi = tid >> 2, qq = tid & 3;     // 64 outputs x 4 lanes
        int rr = oi >> 5, j = oi & 31;
        int r = r0 + rr;
        const float4* gr = (const float4*)(g2 + rr * 128);
        float p = 0.f;
        #pragma unroll
        for (int u4 = qq * 8; u4 < qq * 8 + 8; u4++) p += dot4(gr[u4], *(const float4*)(w3s + j * 132 + u4 * 4));
        p += __shfl_down(p, 2, 4);
        p += __shfl_down(p, 1, 4);
        if (qq == 0) {
            float val = x[r * 32 + j] + b3v + p;
            if (r < S) {
                out_m1[s * 384 + r * 32 + j] = val;
                if (i1 >= 0) outp[((s * 3 + i1) * 12 + r) * 32 + j] = val;
            } else {
                out_m2[s * 384 + (r - S) * 32 + j] = val;
                if (i2 >= 0) outp[((s * 3 + i2) * 12 + (r - S)) * 32 + j] = val;
            }
        }
    }
}

extern "C" void kernel_launch(void* const* d_in, const int* in_sizes, int n_in,
                              void* d_out, int out_size, void* d_ws, size_t ws_size,
                              hipStream_t stream) {
    const float* input_t = (const float*)d_in[0];
    const float* input_s = (const float*)d_in[1];
    const float* s2g_w   = (const float*)d_in[2];
    const float* s2g_b   = (const float*)d_in[3];
    const float* g2g_w   = (const float*)d_in[4];
    const float* g2g_b   = (const float*)d_in[5];
    const float* lnx_g   = (const float*)d_in[6];
    const float* lnx_b   = (const float*)d_in[7];
    const float* lny_g   = (const float*)d_in[8];
    const float* lny_b   = (const float*)d_in[9];
    const float* lnf_g   = (const float*)d_in[10];
    const float* lnf_b   = (const float*)d_in[11];
    const float* wq_w    = (const float*)d_in[12];
    const float* wq_b    = (const float*)d_in[13];
    const float* wk_w    = (const float*)d_in[14];
    const float* wk_b    = (const float*)d_in[15];
    const float* wv_w    = (const float*)d_in[16];
    const float* wv_b    = (const float*)d_in[17];
    const float* l1_w    = (const float*)d_in[18];
    const float* l1_b    = (const float*)d_in[19];
    const float* l2_w    = (const float*)d_in[20];
    const float* l2_b    = (const float*)d_in[21];
    const float* l3_w    = (const float*)d_in[22];
    const float* l3_b    = (const float*)d_in[23];

    float* ws = (float*)d_ws;
    float* gi    = ws;                       // 3*12240 = 36720
    float* xbuf  = ws + 36720;               // 3*2*4608 = 27648
    float* xpart = ws + 36720 + 27648;       // 12*16*768 = 147456
    float* outp  = (float*)d_out;

    k_prep<<<144, 256, 0, stream>>>(input_t, input_s, s2g_w, s2g_b, gi);
    k_g2g<<<3456, 256, 0, stream>>>(g2g_w, g2g_b, gi, xbuf);

    int par[3] = {0, 0, 0};
    const int pairs[3][2] = {{0, 1}, {2, 0}, {1, 2}};
    for (int l = 0; l < 8; l++) {
        for (int pp = 0; pp < 3; pp++) {
            int m1 = pairs[pp][0], m2 = pairs[pp][1];
            float* in1  = xbuf + m1 * 9216 + par[m1] * 4608;
            float* in2  = xbuf + m2 * 9216 + par[m2] * 4608;
            float* out1 = xbuf + m1 * 9216 + (1 - par[m1]) * 4608;
            float* out2 = xbuf + m2 * 9216 + (1 - par[m2]) * 4608;
            int i1 = -1, i2 = -1;
            if (l == 7 && pp == 1) i2 = 0;
            if (l == 7 && pp == 2) { i1 = 1; i2 = 2; }
            k_attn<<<192, 512, 0, stream>>>(in1, in2,
                lnx_g, lnx_b, lny_g, lny_b,
                wq_w, wq_b, wk_w, wk_b, wv_w, wv_b,
                l1_w, xpart, l);
            k_ffn<<<144, 256, 0, stream>>>(in1, in2, xpart, l1_b,
                lnf_g, lnf_b, l2_w, l2_b, l3_w, l3_b,
                out1, out2, outp, i1, i2, l);
            par[m1] ^= 1; par[m2] ^= 1;
        }
    }
}

// Round 16
// 424.825 us; speedup vs baseline: 3.1551x; 1.0071x over previous
//
#include <hip/hip_runtime.h>
#include <hip/hip_bf16.h>
#include <math.h>

// Sizes
#define S 12
#define C 32
#define T 7
#define GIN 12240         // S*S*(T*S+1)
#define GOUT 4608         // S*S*C
#define EPS 1e-5f

typedef float nfloat4 __attribute__((ext_vector_type(4)));   // native vec for nontemporal builtins

__device__ __forceinline__ float dot4(float4 a, float4 b) {
    return a.x * b.x + a.y * b.y + a.z * b.z + a.w * b.w;
}

// ---------------- prep: build gi[3][12240] ----------------
__global__ __launch_bounds__(256) void k_prep(
    const float* __restrict__ it, const float* __restrict__ is_,
    const float* __restrict__ s2w, const float* __restrict__ s2b,
    float* __restrict__ gi)
{
    int idx = blockIdx.x * 256 + threadIdx.x;
    if (idx >= 3 * GIN) return;
    int i = idx / GIN, rem = idx % GIN;
    int ab = rem / 85, e = rem % 85;
    int a = ab / S, b = ab % S;
    float val;
    if (e < 84) {
        int k = e / T, t = e % T;
        int x, y, z;
        if (i == 0)      { x = a; y = b; z = k; }
        else if (i == 1) { x = b; y = k; z = a; }
        else             { x = k; y = a; z = b; }
        val = it[((t * S + x) * S + y) * S + z];
    } else {
        float acc = s2b[i * 144 + ab];
        const float* wr = s2w + (i * 144 + ab) * 8;
        #pragma unroll
        for (int u = 0; u < 8; u++) acc += wr[u] * is_[u];
        val = acc;
    }
    gi[idx] = val;
}

// ---------------- g2g: x[i] = W[i] @ gi[i] + b[i], one wave per row ----------------
__global__ __launch_bounds__(256) void k_g2g(
    const float* __restrict__ W, const float* __restrict__ gb,
    const float* __restrict__ gi, float* __restrict__ xbuf)
{
    int wave = threadIdx.x >> 6;
    int lane = threadIdx.x & 63;
    int r = blockIdx.x * 4 + wave;          // 0..13823
    int i = r / GOUT, rr = r % GOUT;
    const nfloat4* Wr = reinterpret_cast<const nfloat4*>(W + (size_t)r * GIN);
    const float4* gv = reinterpret_cast<const float4*>(gi + i * GIN);
    float acc0 = 0.f, acc1 = 0.f;
    int k = lane;
    for (; k + 64 < GIN / 4; k += 128) {
        nfloat4 w0 = __builtin_nontemporal_load(&Wr[k]);
        float4 g0 = gv[k];
        acc0 += w0.x * g0.x + w0.y * g0.y + w0.z * g0.z + w0.w * g0.w;
        nfloat4 w1 = __builtin_nontemporal_load(&Wr[k + 64]);
        float4 g1 = gv[k + 64];
        acc1 += w1.x * g1.x + w1.y * g1.y + w1.z * g1.z + w1.w * g1.w;
    }
    if (k < GIN / 4) {
        nfloat4 w0 = __builtin_nontemporal_load(&Wr[k]);
        float4 g0 = gv[k];
        acc0 += w0.x * g0.x + w0.y * g0.y + w0.z * g0.z + w0.w * g0.w;
    }
    float acc = acc0 + acc1;
    #pragma unroll
    for (int off = 32; off; off >>= 1) acc += __shfl_down(acc, off, 64);
    if (lane == 0) xbuf[i * (2 * GOUT) + rr] = acc + gb[r];   // parity 0
}

// ---------------- K1: per (slice, head), 512 threads, 3 barriers ----------------
// R15 + wave-local scores: wave w owns rows {2w,2w+1} (+{16+2w,17+2w} for w<4);
// it computes those rows' scores, o, and W1 with no barrier after QKV
// (same-wave LDS in-order; q rows are same-wave-written; kk/vv covered by barrier #3).
__global__ __launch_bounds__(512) void k_attn(
    const float* __restrict__ xm1, const float* __restrict__ xm2,
    const float* __restrict__ lnxg, const float* __restrict__ lnxb,
    const float* __restrict__ lnyg, const float* __restrict__ lnyb,
    const float* __restrict__ wqw, const float* __restrict__ wqb,
    const float* __restrict__ wkw, const float* __restrict__ wkb,
    const float* __restrict__ wvw, const float* __restrict__ wvb,
    const float* __restrict__ l1w,
    float* __restrict__ xpart, int l)
{
    int s = blockIdx.x >> 4, h = blockIdx.x & 15;
    int tid = threadIdx.x;
    int ls = l * S + s;
    int jj = tid & 31;
    int r0 = tid >> 5;                     // row for pass A (0..15)
    __shared__ float xn[768], yn[768], vv[768], oo[768];
    __shared__ float q[864], kk[864];      // 24 rows x stride 36 (padded)
    __shared__ float sc[576];
    __shared__ float red[16];
    __shared__ float wqs[1152], wks[1152], wvs[1152], w1s[1152];   // [32][36] padded

    // ---- a-loads issued FIRST ----
    float av0 = (r0 < S) ? xm1[s * 384 + r0 * 32 + jj]
                         : xm2[(r0 - S) * 384 + s * 32 + jj];
    float av1 = 0.f;
    if (tid < 256) av1 = xm2[(((tid + 512) >> 5) - S) * 384 + s * 32 + jj];  // rows 16..23

    // ---- prefetch: LN params, biases, weights (weights by tid<256) ----
    const float* gx = lnxg + ls * 768; const float* bx = lnxb + ls * 768;
    const float* gy = lnyg + ls * 768; const float* by = lnyb + ls * 768;
    float gx0 = gx[tid], bx0 = bx[tid], gy0 = gy[tid], by0 = by[tid];
    float gx1 = 0.f, bx1 = 0.f, gy1 = 0.f, by1 = 0.f;
    if (tid < 256) { gx1 = gx[tid + 512]; bx1 = bx[tid + 512]; gy1 = gy[tid + 512]; by1 = by[tid + 512]; }
    float qbv = wqb[ls * 512 + h * 32 + jj];
    float kbv = wkb[ls * 512 + h * 32 + jj];
    float vbv = wvb[ls * 512 + h * 32 + jj];
    float4 pq, pk, pv, p1;
    int wrow = tid >> 3, wcol = (tid << 2) & 31;
    if (tid < 256) {
        pq = *(const float4*)(wqw + (size_t)ls * 16384 + h * 1024 + tid * 4);
        pk = *(const float4*)(wkw + (size_t)ls * 16384 + h * 1024 + tid * 4);
        pv = *(const float4*)(wvw + (size_t)ls * 16384 + h * 1024 + tid * 4);
        p1 = *(const float4*)(l1w + (size_t)ls * 16384 + h * 32 + wrow * 512 + wcol);
    }

    // ---- LN stats from registers (8 waves) ----
    {
        float s1 = av0 + av1;
        float s2 = av0 * av0 + av1 * av1;
        #pragma unroll
        for (int off = 32; off; off >>= 1) { s1 += __shfl_down(s1, off, 64); s2 += __shfl_down(s2, off, 64); }
        if ((tid & 63) == 0) { red[(tid >> 6) * 2] = s1; red[(tid >> 6) * 2 + 1] = s2; }
    }
    __syncthreads();                                   // barrier #1

    float mu, rs;
    {
        float t1 = 0.f, t2 = 0.f;
        #pragma unroll
        for (int w = 0; w < 8; w++) { t1 += red[w * 2]; t2 += red[w * 2 + 1]; }
        mu = t1 * (1.f / 768.f);
        float var = t2 * (1.f / 768.f) - mu * mu;
        rs = rsqrtf(var + EPS);
    }

    // ---- LN apply from registers + stage weights ----
    {
        float zn = (av0 - mu) * rs;
        xn[tid] = zn * gx0 + bx0;
        yn[tid] = zn * gy0 + by0;
    }
    if (tid < 256) {
        float zn = (av1 - mu) * rs;
        xn[tid + 512] = zn * gx1 + bx1;
        yn[tid + 512] = zn * gy1 + by1;
        *(float4*)(wqs + wrow * 36 + wcol) = pq;
        *(float4*)(wks + wrow * 36 + wcol) = pk;
        *(float4*)(wvs + wrow * 36 + wcol) = pv;
        *(float4*)(w1s + wrow * 36 + wcol) = p1;
    }
    __syncthreads();                                   // barrier #2

    // ---- fused QKV: pass A (row r0) + pass B (row r0+16, tid<256) ----
    {
        float aqA = qbv, akA = kbv, avA = vbv;
        float aqB = qbv, akB = kbv, avB = vbv;
        int rB = (tid >> 5) + 16;
        #pragma unroll
        for (int c4 = 0; c4 < 8; c4++) {
            float4 wq4 = *(const float4*)(wqs + jj * 36 + c4 * 4);
            float4 wk4 = *(const float4*)(wks + jj * 36 + c4 * 4);
            float4 wv4 = *(const float4*)(wvs + jj * 36 + c4 * 4);
            float4 xvA = *(const float4*)(xn + r0 * 32 + c4 * 4);
            float4 yvA = *(const float4*)(yn + r0 * 32 + c4 * 4);
            aqA += dot4(xvA, wq4); akA += dot4(yvA, wk4); avA += dot4(yvA, wv4);
            if (tid < 256) {
                float4 xvB = *(const float4*)(xn + rB * 32 + c4 * 4);
                float4 yvB = *(const float4*)(yn + rB * 32 + c4 * 4);
                aqB += dot4(xvB, wq4); akB += dot4(yvB, wk4); avB += dot4(yvB, wv4);
            }
        }
        q[r0 * 36 + jj] = aqA; kk[r0 * 36 + jj] = akA; vv[r0 * 32 + jj] = avA;
        if (tid < 256) { q[rB * 36 + jj] = aqB; kk[rB * 36 + jj] = akB; vv[rB * 32 + jj] = avB; }
    }
    __syncthreads();                                   // barrier #3 (kk, vv global)

    // ---- wave-local: scores -> o -> W1, no further barriers ----
    int wv = tid >> 6;
    int lane = tid & 63;

    // scores for own rows (lanes 0..47: rl = lane/24, j = lane%24)
    if (lane < 48) {
        int rl = lane / 24, j = lane - rl * 24;
        int r = 2 * wv + rl;
        {
            const float4* qr = (const float4*)(q + r * 36);
            const float4* kr = (const float4*)(kk + j * 36);
            float acc = 0.f;
            #pragma unroll
            for (int c4 = 0; c4 < 8; c4++) acc += dot4(qr[c4], kr[c4]);
            sc[r * 24 + j] = acc * 0.17677669529663687f;   // 1/sqrt(32)
        }
        if (wv < 4) {
            int r2 = 16 + 2 * wv + rl;
            const float4* qr = (const float4*)(q + r2 * 36);
            const float4* kr = (const float4*)(kk + j * 36);
            float acc = 0.f;
            #pragma unroll
            for (int c4 = 0; c4 < 8; c4++) acc += dot4(qr[c4], kr[c4]);
            sc[r2 * 24 + j] = acc * 0.17677669529663687f;
        }
    }

    // o = sc @ v for own rows (same-wave LDS RAW: in-order pipeline)
    {
        const float* srA = sc + r0 * 24;
        float accA = 0.f;
        #pragma unroll
        for (int j = 0; j < 24; j++) accA += srA[j] * vv[j * 32 + jj];
        oo[r0 * 32 + jj] = accA;
        if (tid < 256) {
            int rB = (tid >> 5) + 16;
            const float* srB = sc + rB * 24;
            float accB = 0.f;
            #pragma unroll
            for (int j = 0; j < 24; j++) accB += srB[j] * vv[j * 32 + jj];
            oo[rB * 32 + jj] = accB;
        }
    }
    // xpart = o @ w1^T (same-wave RAW on oo)
    {
        float* xp = xpart + (s * 16 + h) * 768;
        const float4* orowA = (const float4*)(oo + r0 * 32);
        float accA = 0.f;
        #pragma unroll
        for (int c4 = 0; c4 < 8; c4++) accA += dot4(orowA[c4], *(const float4*)(w1s + jj * 36 + c4 * 4));
        xp[r0 * 32 + jj] = accA;
        if (tid < 256) {
            int rB = (tid >> 5) + 16;
            const float4* orowB = (const float4*)(oo + rB * 32);
            float accB = 0.f;
            #pragma unroll
            for (int c4 = 0; c4 < 8; c4++) accB += dot4(orowB[c4], *(const float4*)(w1s + jj * 36 + c4 * 4));
            xp[rB * 32 + jj] = accB;
        }
    }
}

// ---------------- K2: r-split FFN, 144 blocks x 256 threads (unchanged R15) ----------------
__global__ __launch_bounds__(256) void k_ffn(
    const float* __restrict__ xm1, const float* __restrict__ xm2,
    const float* __restrict__ xpart,
    const float* __restrict__ l1b,
    const float* __restrict__ lnfg, const float* __restrict__ lnfb,
    const float* __restrict__ l2w, const float* __restrict__ l2b,
    const float* __restrict__ l3w, const float* __restrict__ l3b,
    float* __restrict__ out_m1, float* __restrict__ out_m2,
    float* __restrict__ outp, int i1, int i2, int l)
{
    int s = blockIdx.x / 12, rg = blockIdx.x % 12;
    int r0 = rg * 2;
    int tid = threadIdx.x;
    int ls = l * S + s;
    int jj = tid & 31;
    __shared__ float x[768], hn2[64], g2[256];
    __shared__ float red[16];
    __shared__ float w2s[4608];    // [128][36] padded
    __shared__ float w3s[4224];    // [32][132] padded

    // ---- prefetch weights + biases + LN params ----
    float4 pw2[4], pw3[4];
    const float4* w2g = (const float4*)(l2w + (size_t)ls * 4096);
    const float4* w3g = (const float4*)(l3w + (size_t)ls * 4096);
    #pragma unroll
    for (int k = 0; k < 4; k++) { pw2[k] = w2g[tid + k * 256]; pw3[k] = w3g[tid + k * 256]; }
    int xr = tid >> 3, xc4 = tid & 7;            // chunk (row, 4-col group), tid<192
    float4 b1v4 = *(const float4*)(l1b + ls * 32 + xc4 * 4);
    float b2v = l2b[ls * 128 + (tid & 127)];
    float b3v = l3b[ls * 32 + ((tid >> 2) & 31)];
    int idxl = (r0 + (tid >> 5)) * 32 + jj;      // valid for tid < 64
    float lg = 0.f, lb = 0.f;
    if (tid < 64) { lg = lnfg[ls * 768 + idxl]; lb = lnfb[ls * 768 + idxl]; }

    // ---- x = a + b1 + sum of 16 head partials (float4), LN stats fused ----
    {
        float s1 = 0.f, s2 = 0.f;
        if (tid < 192) {
            float4 acc = (xr < S) ? *(const float4*)(xm1 + s * 384 + xr * 32 + xc4 * 4)
                                  : *(const float4*)(xm2 + (xr - S) * 384 + s * 32 + xc4 * 4);
            acc.x += b1v4.x; acc.y += b1v4.y; acc.z += b1v4.z; acc.w += b1v4.w;
            const float* xp = xpart + s * 16 * 768 + tid * 4;
            #pragma unroll
            for (int hh = 0; hh < 16; hh++) {
                float4 p = *(const float4*)(xp + hh * 768);
                acc.x += p.x; acc.y += p.y; acc.z += p.z; acc.w += p.w;
            }
            *(float4*)(x + tid * 4) = acc;
            s1 = acc.x + acc.y + acc.z + acc.w;
            s2 = acc.x * acc.x + acc.y * acc.y + acc.z * acc.z + acc.w * acc.w;
        }
        #pragma unroll
        for (int off = 32; off; off >>= 1) { s1 += __shfl_down(s1, off, 64); s2 += __shfl_down(s2, off, 64); }
        if ((tid & 63) == 0) { red[(tid >> 6) * 2] = s1; red[(tid >> 6) * 2 + 1] = s2; }
    }
    __syncthreads();

    float mu, rs;
    {
        float t1 = red[0] + red[2] + red[4] + red[6];
        float t2 = red[1] + red[3] + red[5] + red[7];
        mu = t1 * (1.f / 768.f);
        float var = t2 * (1.f / 768.f) - mu * mu;
        rs = rsqrtf(var + EPS);
    }

    // ---- LN apply for own 2 rows (prefetched gains) ----
    if (tid < 64) hn2[tid] = (x[idxl] - mu) * rs * lg + lb;

    // ---- stage W2/W3 to LDS (padded rows) ----
    #pragma unroll
    for (int k = 0; k < 4; k++) {
        int e = tid + k * 256;
        *(float4*)(w2s + (e >> 3) * 36 + ((e << 2) & 31)) = pw2[k];
        *(float4*)(w3s + (e >> 5) * 132 + ((e << 2) & 127)) = pw3[k];
    }
    __syncthreads();

    // ---- g2 = gelu(hn2 @ W2^T + b2): 2 rows x 128 dots, 1/thread ----
    {
        int rr = tid >> 7, u = tid & 127;
        const float4* hr = (const float4*)(hn2 + rr * 32);
        float acc = b2v;
        #pragma unroll
        for (int c4 = 0; c4 < 8; c4++) acc += dot4(hr[c4], *(const float4*)(w2s + u * 36 + c4 * 4));
        g2[rr * 128 + u] = acc * 0.5f * (1.f + erff(acc * 0.70710678118654752f));
    }
    __syncthreads();

    // ---- out = x + g2 @ W3^T + b3 for own 2 rows (4-way u-split per output) ----
    {
        int oi = tid >> 2, qq = tid & 3;     // 64 outputs x 4 lanes
        int rr = oi >> 5, j = oi & 31;
        int r = r0 + rr;
        const float4* gr = (const float4*)(g2 + rr * 128);
        float p = 0.f;
        #pragma unroll
        for (int u4 = qq * 8; u4 < qq * 8 + 8; u4++) p += dot4(gr[u4], *(const float4*)(w3s + j * 132 + u4 * 4));
        p += __shfl_down(p, 2, 4);
        p += __shfl_down(p, 1, 4);
        if (qq == 0) {
            float val = x[r * 32 + j] + b3v + p;
            if (r < S) {
                out_m1[s * 384 + r * 32 + j] = val;
                if (i1 >= 0) outp[((s * 3 + i1) * 12 + r) * 32 + j] = val;
            } else {
                out_m2[s * 384 + (r - S) * 32 + j] = val;
                if (i2 >= 0) outp[((s * 3 + i2) * 12 + (r - S)) * 32 + j] = val;
            }
        }
    }
}

extern "C" void kernel_launch(void* const* d_in, const int* in_sizes, int n_in,
                              void* d_out, int out_size, void* d_ws, size_t ws_size,
                              hipStream_t stream) {
    const float* input_t = (const float*)d_in[0];
    const float* input_s = (const float*)d_in[1];
    const float* s2g_w   = (const float*)d_in[2];
    const float* s2g_b   = (const float*)d_in[3];
    const float* g2g_w   = (const float*)d_in[4];
    const float* g2g_b   = (const float*)d_in[5];
    const float* lnx_g   = (const float*)d_in[6];
    const float* lnx_b   = (const float*)d_in[7];
    const float* lny_g   = (const float*)d_in[8];
    const float* lny_b   = (const float*)d_in[9];
    const float* lnf_g   = (const float*)d_in[10];
    const float* lnf_b   = (const float*)d_in[11];
    const float* wq_w    = (const float*)d_in[12];
    const float* wq_b    = (const float*)d_in[13];
    const float* wk_w    = (const float*)d_in[14];
    const float* wk_b    = (const float*)d_in[15];
    const float* wv_w    = (const float*)d_in[16];
    const float* wv_b    = (const float*)d_in[17];
    const float* l1_w    = (const float*)d_in[18];
    const float* l1_b    = (const float*)d_in[19];
    const float* l2_w    = (const float*)d_in[20];
    const float* l2_b    = (const float*)d_in[21];
    const float* l3_w    = (const float*)d_in[22];
    const float* l3_b    = (const float*)d_in[23];

    float* ws = (float*)d_ws;
    float* gi    = ws;                       // 3*12240 = 36720
    float* xbuf  = ws + 36720;               // 3*2*4608 = 27648
    float* xpart = ws + 36720 + 27648;       // 12*16*768 = 147456
    float* outp  = (float*)d_out;

    k_prep<<<144, 256, 0, stream>>>(input_t, input_s, s2g_w, s2g_b, gi);
    k_g2g<<<3456, 256, 0, stream>>>(g2g_w, g2g_b, gi, xbuf);

    int par[3] = {0, 0, 0};
    const int pairs[3][2] = {{0, 1}, {2, 0}, {1, 2}};
    for (int l = 0; l < 8; l++) {
        for (int pp = 0; pp < 3; pp++) {
            int m1 = pairs[pp][0], m2 = pairs[pp][1];
            float* in1  = xbuf + m1 * 9216 + par[m1] * 4608;
            float* in2  = xbuf + m2 * 9216 + par[m2] * 4608;
            float* out1 = xbuf + m1 * 9216 + (1 - par[m1]) * 4608;
            float* out2 = xbuf + m2 * 9216 + (1 - par[m2]) * 4608;
            int i1 = -1, i2 = -1;
            if (l == 7 && pp == 1) i2 = 0;
            if (l == 7 && pp == 2) { i1 = 1; i2 = 2; }
            k_attn<<<192, 512, 0, stream>>>(in1, in2,
                lnx_g, lnx_b, lny_g, lny_b,
                wq_w, wq_b, wk_w, wk_b, wv_w, wv_b,
                l1_w, xpart, l);
            k_ffn<<<144, 256, 0, stream>>>(in1, in2, xpart, l1_b,
                lnf_g, lnf_b, l2_w, l2_b, l3_w, l3_b,
                out1, out2, outp, i1, i2, l);
            par[m1] ^= 1; par[m2] ^= 1;
        }
    }
}